// Round 8
// baseline (45688.980 us; speedup 1.0000x reference)
//
#include <hip/hip_runtime.h>

// ---------------------------------------------------------------------------
// LayerNorm-LSTM (depth=2) + FC, MI355X. Split-bf16 (hi/lo) 3-term MFMA
// everywhere (incl. recurrent GEMM). One fused cooperative kernel per step:
// hh GEMM (Whh hi+lo staged in 128KB LDS) + LNx2 + gates + cell-LN + h/Y.
// Custom monotonic spin-barriers for the two LN-stats grid syncs.
// ---------------------------------------------------------------------------

typedef __attribute__((ext_vector_type(8))) short short8;
typedef __attribute__((ext_vector_type(8))) __bf16 bf16x8;
typedef __attribute__((ext_vector_type(4))) float f32x4;
typedef __attribute__((ext_vector_type(4))) unsigned short us4;

#define B_ 64
#define T_ 512
#define D_ 1024
#define H_ 1024
#define FH_ 4096
#define LAG_ 16
#define NS_ (T_ + LAG_)        // 528 steps
#define RCH_ (B_ * 16)         // 1024 rows per chunk window

// fused kernel LDS: 128KB Whh hi+lo frag + hhp tile [64][33] fp32
#define SMEM_WHH 131072
#define SMEM_TOTAL (SMEM_WHH + 64 * 33 * 4)

typedef const __attribute__((address_space(1))) unsigned int* gas_ptr;
typedef __attribute__((address_space(3))) unsigned int* las_ptr;
#define GLOAD_LDS16(g, l) \
  __builtin_amdgcn_global_load_lds((gas_ptr)(g), (las_ptr)(l), 16, 0, 0)

static __device__ __forceinline__ unsigned short f2bf(float f) {
  unsigned int u = __builtin_bit_cast(unsigned int, f);
  u += 0x7FFFu + ((u >> 16) & 1u);   // round-to-nearest-even
  return (unsigned short)(u >> 16);
}
static __device__ __forceinline__ float bf2f(unsigned short u) {
  unsigned int x = ((unsigned int)u) << 16;
  return __builtin_bit_cast(float, x);
}

// ---------------- split-cast fp32 -> (hi, lo) bf16 ----------------
__global__ void cast_split_k(const float4* __restrict__ in,
                             us4* __restrict__ hi, us4* __restrict__ lo, int n4) {
  int i = blockIdx.x * 256 + threadIdx.x;
  if (i < n4) {
    float4 v = in[i];
    us4 h, l;
    h[0] = f2bf(v.x); l[0] = f2bf(v.x - bf2f(h[0]));
    h[1] = f2bf(v.y); l[1] = f2bf(v.y - bf2f(h[1]));
    h[2] = f2bf(v.z); l[2] = f2bf(v.z - bf2f(h[2]));
    h[3] = f2bf(v.w); l[3] = f2bf(v.w - bf2f(h[3]));
    hi[i] = h; lo[i] = l;
  }
}

// ------ transpose-split input [B][T][D] f32 -> [T][B][D] (hi, lo) bf16 -----
__global__ void transpose_split_k(const float4* __restrict__ x,
                                  us4* __restrict__ hi, us4* __restrict__ lo) {
  int i = blockIdx.x * 256 + threadIdx.x;
  int d4  = i & 255;
  int rem = i >> 8;
  int b = rem & 63;
  int t = rem >> 6;
  float4 v = x[((size_t)(b * T_ + t) << 8) + d4];
  us4 h, l;
  h[0] = f2bf(v.x); l[0] = f2bf(v.x - bf2f(h[0]));
  h[1] = f2bf(v.y); l[1] = f2bf(v.y - bf2f(h[1]));
  h[2] = f2bf(v.z); l[2] = f2bf(v.z - bf2f(h[2]));
  h[3] = f2bf(v.w); l[3] = f2bf(v.w - bf2f(h[3]));
  size_t o = ((size_t)(t * B_ + b) << 8) + d4;
  hi[o] = h; lo[o] = l;
}

// ------ fragment-ordered Whh (hi AND lo), gate-interleaved -----------------
// chunk i (16B): lane=i&63, kc=(i>>6)&31, g=(i>>11)&1, sel=(i>>12)&1,
// j=(i>>13)&127, layer=(i>>20)&1. fc=lane&15, q=g*2+(fc>>3),
// gc=q*1024+j*8+(fc&7), k0=kc*32+(lane>>4)*8.
__global__ void whh_frag3_k(const float* __restrict__ w_hh,
                            unsigned short* __restrict__ frag) {
  int i = blockIdx.x * 256 + threadIdx.x;    // 2,097,152 chunks
  int lane = i & 63;
  int kc   = (i >> 6) & 31;
  int g    = (i >> 11) & 1;
  int sel  = (i >> 12) & 1;
  int j    = (i >> 13) & 127;
  int layer= (i >> 20) & 1;
  int fc = lane & 15;
  int gc = (g * 2 + (fc >> 3)) * 1024 + j * 8 + (fc & 7);
  int k0 = kc * 32 + (lane >> 4) * 8;
  const float* src = w_hh + ((size_t)layer * FH_ + gc) * 1024 + k0;
  short8 o;
#pragma unroll
  for (int e = 0; e < 8; ++e) {
    float v = src[e];
    unsigned short h = f2bf(v);
    o[e] = sel ? (short)f2bf(v - bf2f(h)) : (short)h;
  }
  *(short8*)(frag + (size_t)i * 8) = o;
}

// ---------------- 3-term split-bf16 GEMM (chunk projections + FC) ----------
template <int FCMODE>
__global__ __launch_bounds__(256) void gemm3_k(
    const unsigned short* __restrict__ Ahi, const unsigned short* __restrict__ Alo,
    const unsigned short* __restrict__ Whi, const unsigned short* __restrict__ Wlo,
    const float* __restrict__ bias, float* __restrict__ out, int K, int N) {
  __shared__ unsigned short lAh[128 * 40];
  __shared__ unsigned short lAl[128 * 40];
  __shared__ unsigned short lWh[128 * 40];
  __shared__ unsigned short lWl[128 * 40];
  int tid = threadIdx.x;
  int l = tid & 63, w = tid >> 6;
  int r0 = blockIdx.y * 128, c0 = blockIdx.x * 128;
  int wr = (w >> 1) * 64, wc = (w & 1) * 64;
  int lr = l & 15, lk = (l >> 4) * 8;
  f32x4 acc[4][4] = {};
  int srow = tid >> 2;
  int scc  = (tid & 3) * 8;

  for (int kt = 0; kt < K; kt += 32) {
#pragma unroll
    for (int i = 0; i < 2; ++i) {
      int row = srow + i * 64;
      size_t aoff = (size_t)(r0 + row) * K + kt + scc;
      size_t woff = (size_t)(c0 + row) * K + kt + scc;
      *(short8*)&lAh[row * 40 + scc] = *(const short8*)(Ahi + aoff);
      *(short8*)&lAl[row * 40 + scc] = *(const short8*)(Alo + aoff);
      *(short8*)&lWh[row * 40 + scc] = *(const short8*)(Whi + woff);
      *(short8*)&lWl[row * 40 + scc] = *(const short8*)(Wlo + woff);
    }
    __syncthreads();
    bf16x8 ah[4], al[4], bh[4], bl[4];
#pragma unroll
    for (int mi = 0; mi < 4; ++mi) {
      ah[mi] = *(bf16x8*)&lAh[(wr + mi * 16 + lr) * 40 + lk];
      al[mi] = *(bf16x8*)&lAl[(wr + mi * 16 + lr) * 40 + lk];
    }
#pragma unroll
    for (int ni = 0; ni < 4; ++ni) {
      bh[ni] = *(bf16x8*)&lWh[(wc + ni * 16 + lr) * 40 + lk];
      bl[ni] = *(bf16x8*)&lWl[(wc + ni * 16 + lr) * 40 + lk];
    }
#pragma unroll
    for (int mi = 0; mi < 4; ++mi)
#pragma unroll
      for (int ni = 0; ni < 4; ++ni) {
        acc[mi][ni] = __builtin_amdgcn_mfma_f32_16x16x32_bf16(ah[mi], bh[ni], acc[mi][ni], 0, 0, 0);
        acc[mi][ni] = __builtin_amdgcn_mfma_f32_16x16x32_bf16(ah[mi], bl[ni], acc[mi][ni], 0, 0, 0);
        acc[mi][ni] = __builtin_amdgcn_mfma_f32_16x16x32_bf16(al[mi], bh[ni], acc[mi][ni], 0, 0, 0);
      }
    __syncthreads();
  }

#pragma unroll
  for (int mi = 0; mi < 4; ++mi)
#pragma unroll
    for (int ni = 0; ni < 4; ++ni)
#pragma unroll
      for (int reg = 0; reg < 4; ++reg) {
        int r = r0 + wr + mi * 16 + (l >> 4) * 4 + reg;
        int c = c0 + wc + ni * 16 + lr;
        float v = acc[mi][ni][reg] + bias[c];
        if (FCMODE) {
          int b = r & 63, t = r >> 6;
          out[((size_t)b * T_ + t) * (size_t)N + c] = v;
        } else {
          out[(size_t)r * N + c] = v;
        }
      }
}

// ---------------- fused per-step kernel ----------------
struct SP {
  const unsigned short* whhF;
  const float *P0, *P1;
  unsigned short *hH, *hL, *XYhi, *XYlo;
  float* cst;
  const float *bhh, *gih, *beih, *ghh, *behh, *gho, *beho;
  float *st1, *st2;      // [2 parity][2 layer][64][4] / [..][64][2]
  unsigned* cnt;         // [2] monotonic barrier counters
  int s; unsigned tgt;
};

static __device__ __forceinline__ void gbar(unsigned* cnt, unsigned tgt, int tid) {
  __syncthreads();                       // all waves' mem ops drained
  if (tid == 0) {
    __threadfence();
    atomicAdd(cnt, 1u);
    while (__hip_atomic_load(cnt, __ATOMIC_RELAXED, __HIP_MEMORY_SCOPE_AGENT) < tgt)
      __builtin_amdgcn_s_sleep(2);
  }
  __syncthreads();
}

__global__ __launch_bounds__(512) void fused_step_k(SP p) {
  extern __shared__ char smem[];
  unsigned short* wl = (unsigned short*)smem;          // 128KB frag slice
  float* ldshh = (float*)(smem + SMEM_WHH);            // [64][33]

  const int tid = threadIdx.x;
  const int blk = blockIdx.x;
  const int layer = blk >> 7;
  const int j = blk & 127;
  const int t0 = layer ? (p.s - LAG_) : p.s;
  const bool active = (t0 >= 0) && (t0 < T_);
  const int l = tid & 63, w = tid >> 6;
  const int lr = l & 15, lq = l >> 4;

  // ---- stage Whh hi+lo slice (128 KB, lane-linear async) ----
  if (active) {
    const unsigned short* gsrc = p.whhF + (((size_t)(layer * 128 + j)) << 16);
#pragma unroll
    for (int r = 0; r < 16; ++r) {
      int c = r * 512 + tid;
      GLOAD_LDS16(gsrc + (size_t)c * 8, wl + (size_t)c * 8);
    }
  }
  __syncthreads();   // drains vmcnt: staging complete

  // ---- hh MFMA: wave w -> rowfrag rf=w>>1 (16 rows), colgroup g=w&1 ----
  if (active) {
    const int rf = w >> 1, g = w & 1;
    const int rowbase = rf * 16;
    const int fc = lr;
    const int q = g * 2 + (fc >> 3);
    const int gc = q * 1024 + j * 8 + (fc & 7);
    const unsigned short* hHb = p.hH + layer * 65536;
    const unsigned short* hLb = p.hL + layer * 65536;
    f32x4 acc = {};
#pragma unroll 8
    for (int kc = 0; kc < 32; ++kc) {
      int k = kc * 32 + lq * 8;
      bf16x8 ah = __builtin_bit_cast(bf16x8, *(const short8*)(hHb + (rowbase + lr) * 1024 + k));
      bf16x8 al = __builtin_bit_cast(bf16x8, *(const short8*)(hLb + (rowbase + lr) * 1024 + k));
      bf16x8 bh = __builtin_bit_cast(bf16x8, *(const short8*)&wl[(size_t)(g * 2048 + kc * 64 + l) * 8]);
      bf16x8 bl = __builtin_bit_cast(bf16x8, *(const short8*)&wl[(size_t)(4096 + g * 2048 + kc * 64 + l) * 8]);
      acc = __builtin_amdgcn_mfma_f32_16x16x32_bf16(ah, bh, acc, 0, 0, 0);
      acc = __builtin_amdgcn_mfma_f32_16x16x32_bf16(al, bh, acc, 0, 0, 0);
      acc = __builtin_amdgcn_mfma_f32_16x16x32_bf16(ah, bl, acc, 0, 0, 0);
    }
    float bhhv = p.bhh[layer * FH_ + gc];
    int bc = q * 8 + (fc & 7);
#pragma unroll
    for (int reg = 0; reg < 4; ++reg)
      ldshh[(rowbase + lq * 4 + reg) * 33 + bc] = acc[reg] + bhhv;
  }
  __syncthreads();

  // ---- stats-1 partials: thread t -> row=t>>3, c8=t&7 ----
  const int row = tid >> 3, c8 = tid & 7;
  const int hcol = j * 8 + c8;
  const int par = p.s & 1;
  float* st1 = p.st1 + ((size_t)par * 2 + layer) * 256;   // [64][4]
  float* st2 = p.st2 + ((size_t)par * 2 + layer) * 128;   // [64][2]
  float ih[4], hh[4];
  if (active) {
    const float* Pb = layer ? p.P1 : p.P0;
    int slot = p.s & 15;
    float s1 = 0, q1 = 0, s2 = 0, q2 = 0;
#pragma unroll
    for (int q = 0; q < 4; ++q) {
      float a = Pb[((size_t)(slot * B_ + row)) * FH_ + q * 1024 + hcol];
      float b = ldshh[row * 33 + q * 8 + c8];
      ih[q] = a; hh[q] = b;
      s1 += a; q1 += a * a; s2 += b; q2 += b * b;
    }
#pragma unroll
    for (int off = 1; off < 8; off <<= 1) {
      s1 += __shfl_xor(s1, off); q1 += __shfl_xor(q1, off);
      s2 += __shfl_xor(s2, off); q2 += __shfl_xor(q2, off);
    }
    if (c8 == 0) {
      atomicAdd(&st1[row * 4 + 0], s1);
      atomicAdd(&st1[row * 4 + 1], q1);
      atomicAdd(&st1[row * 4 + 2], s2);
      atomicAdd(&st1[row * 4 + 3], q2);
    }
  }
  gbar(p.cnt, p.tgt, tid);

  // ---- LN x2 + gates + cell update; stats-2 partials ----
  float cv = 0.0f, ogate = 0.0f;
  if (active) {
    float S1 = __hip_atomic_load(&st1[row * 4 + 0], __ATOMIC_RELAXED, __HIP_MEMORY_SCOPE_AGENT);
    float Q1 = __hip_atomic_load(&st1[row * 4 + 1], __ATOMIC_RELAXED, __HIP_MEMORY_SCOPE_AGENT);
    float S2 = __hip_atomic_load(&st1[row * 4 + 2], __ATOMIC_RELAXED, __HIP_MEMORY_SCOPE_AGENT);
    float Q2 = __hip_atomic_load(&st1[row * 4 + 3], __ATOMIC_RELAXED, __HIP_MEMORY_SCOPE_AGENT);
    const float inv4h = 1.0f / 4096.0f;
    float m1 = S1 * inv4h, m2 = S2 * inv4h;
    float i1 = rsqrtf(Q1 * inv4h - m1 * m1 + 1e-5f);
    float i2 = rsqrtf(Q2 * inv4h - m2 * m2 + 1e-5f);
    float pre[4];
#pragma unroll
    for (int q = 0; q < 4; ++q) {
      int gc = layer * FH_ + q * 1024 + hcol;
      pre[q] = p.gih[gc] * (ih[q] - m1) * i1 + p.beih[gc]
             + p.ghh[gc] * (hh[q] - m2) * i2 + p.behh[gc];
    }
    float iG = 1.0f / (1.0f + __expf(-pre[0]));
    float fG = 1.0f / (1.0f + __expf(-pre[1]));
    float oG = 1.0f / (1.0f + __expf(-pre[2]));
    float gG = tanhf(pre[3]);
    size_t cidx = ((size_t)(layer * B_ + row)) * H_ + hcol;
    cv = fG * p.cst[cidx] + iG * gG;
    p.cst[cidx] = cv;
    ogate = oG;
    float sc = cv, sq = cv * cv;
#pragma unroll
    for (int off = 1; off < 8; off <<= 1) {
      sc += __shfl_xor(sc, off); sq += __shfl_xor(sq, off);
    }
    if (c8 == 0) {
      atomicAdd(&st2[row * 2 + 0], sc);
      atomicAdd(&st2[row * 2 + 1], sq);
    }
  }
  gbar(p.cnt + 1, p.tgt, tid);

  // ---- cell-LN + output ----
  if (active) {
    float S3 = __hip_atomic_load(&st2[row * 2 + 0], __ATOMIC_RELAXED, __HIP_MEMORY_SCOPE_AGENT);
    float Q3 = __hip_atomic_load(&st2[row * 2 + 1], __ATOMIC_RELAXED, __HIP_MEMORY_SCOPE_AGENT);
    const float invh = 1.0f / 1024.0f;
    float m3 = S3 * invh;
    float i3 = rsqrtf(Q3 * invh - m3 * m3 + 1e-5f);
    int hidx = layer * H_ + hcol;
    float hy = ogate * tanhf((cv - m3) * i3 * p.gho[hidx] + p.beho[hidx]);
    unsigned short hv = f2bf(hy);
    unsigned short lv = f2bf(hy - bf2f(hv));
    size_t ho = ((size_t)(layer * B_ + row)) * H_ + hcol;
    p.hH[ho] = hv; p.hL[ho] = lv;
    size_t yo = ((size_t)t0 * B_ + row) * H_ + hcol;
    p.XYhi[yo] = hv; p.XYlo[yo] = lv;
  }

  // ---- tail: zero OPPOSITE parity stats for next step (stream-ordered) ----
  if (blk == 0) {
    int op = (p.s + 1) & 1;
    float* z1 = p.st1 + (size_t)op * 512;
    float* z2 = p.st2 + (size_t)op * 256;
    __hip_atomic_store(&z1[tid], 0.0f, __ATOMIC_RELAXED, __HIP_MEMORY_SCOPE_AGENT);
    if (tid < 256)
      __hip_atomic_store(&z2[tid], 0.0f, __ATOMIC_RELAXED, __HIP_MEMORY_SCOPE_AGENT);
  }
}

// ---------------------------------------------------------------------------
extern "C" void kernel_launch(void* const* d_in, const int* in_sizes, int n_in,
                              void* d_out, int out_size, void* d_ws, size_t ws_size,
                              hipStream_t stream) {
  const float* x    = (const float*)d_in[0];
  const float* w_ih = (const float*)d_in[1];
  const float* b_ih = (const float*)d_in[2];
  const float* w_hh = (const float*)d_in[3];
  const float* b_hh = (const float*)d_in[4];
  const float* g_ih = (const float*)d_in[5];
  const float* be_ih= (const float*)d_in[6];
  const float* g_hh = (const float*)d_in[7];
  const float* be_hh= (const float*)d_in[8];
  const float* g_ho = (const float*)d_in[9];
  const float* be_ho= (const float*)d_in[10];
  const float* fc_w = (const float*)d_in[11];
  const float* fc_b = (const float*)d_in[12];
  float* out = (float*)d_out;
  (void)ws_size; (void)in_sizes; (void)n_in; (void)out_size;

  // workspace carve-up (~230 MB)
  char* wsb = (char*)d_ws;
  size_t off = 0;
  unsigned short* wihHi  = (unsigned short*)(wsb + off); off += 16777216;
  unsigned short* wihLo  = (unsigned short*)(wsb + off); off += 16777216;
  unsigned short* whhF   = (unsigned short*)(wsb + off); off += 33554432;  // hi+lo frag
  unsigned short* fcHi   = (unsigned short*)(wsb + off); off += 2097152;
  unsigned short* fcLo   = (unsigned short*)(wsb + off); off += 2097152;
  unsigned short* XYhi   = (unsigned short*)(wsb + off); off += 67108864;  // [T][64][1024] X->Y0->Y1
  unsigned short* XYlo   = (unsigned short*)(wsb + off); off += 67108864;
  float* P0              = (float*)(wsb + off); off += (size_t)16 * B_ * FH_ * 4; // 16 MB
  float* P1              = (float*)(wsb + off); off += (size_t)16 * B_ * FH_ * 4; // 16 MB
  unsigned short* hH     = (unsigned short*)(wsb + off); off += 262144;
  unsigned short* hL     = (unsigned short*)(wsb + off); off += 262144;
  float* cst             = (float*)(wsb + off); off += 524288;
  float* st1             = (float*)(wsb + off); off += 4096;   // [2][2][64][4]
  float* st2             = (float*)(wsb + off); off += 2048;   // [2][2][64][2]
  unsigned* cnt          = (unsigned*)(wsb + off); off += 256; // [2] counters

  // --- weight prep ---
  {
    int n4 = 2 * FH_ * D_ / 4;
    cast_split_k<<<(n4 + 255) / 256, 256, 0, stream>>>((const float4*)w_ih, (us4*)wihHi, (us4*)wihLo, n4);
    int nf = H_ * H_ / 4;
    cast_split_k<<<(nf + 255) / 256, 256, 0, stream>>>((const float4*)fc_w, (us4*)fcHi, (us4*)fcLo, nf);
    int nx = T_ * B_ * D_ / 4;
    transpose_split_k<<<nx / 256, 256, 0, stream>>>((const float4*)x, (us4*)XYhi, (us4*)XYlo);
    whh_frag3_k<<<8192, 256, 0, stream>>>(w_hh, whhF);
  }

  // --- state init (captured in graph; re-runs each replay) ---
  hipMemsetAsync(hH, 0, 262144, stream);
  hipMemsetAsync(hL, 0, 262144, stream);
  hipMemsetAsync(cst, 0, 524288, stream);
  hipMemsetAsync(st1, 0, 4096 + 2048 + 256, stream);  // st1+st2+cnt contiguous

  hipFuncSetAttribute(reinterpret_cast<const void*>(fused_step_k),
                      hipFuncAttributeMaxDynamicSharedMemorySize, SMEM_TOTAL);

  // --- recurrence: one fused cooperative launch per step ---
  SP prm;
  prm.whhF = whhF; prm.P0 = P0; prm.P1 = P1;
  prm.hH = hH; prm.hL = hL; prm.XYhi = XYhi; prm.XYlo = XYlo;
  prm.cst = cst;
  prm.bhh = b_hh; prm.gih = g_ih; prm.beih = be_ih;
  prm.ghh = g_hh; prm.behh = be_hh; prm.gho = g_ho; prm.beho = be_ho;
  prm.st1 = st1; prm.st2 = st2; prm.cnt = cnt;

  for (int s = 0; s < NS_; ++s) {
    if ((s & 15) == 0) {
      if (s < T_) {
        gemm3_k<0><<<dim3(FH_ / 128, RCH_ / 128), 256, 0, stream>>>(
            XYhi + (size_t)s * B_ * D_, XYlo + (size_t)s * B_ * D_,
            wihHi, wihLo, b_ih, P0, D_, FH_);
      }
      if (s >= LAG_) {
        gemm3_k<0><<<dim3(FH_ / 128, RCH_ / 128), 256, 0, stream>>>(
            XYhi + (size_t)(s - LAG_) * B_ * D_, XYlo + (size_t)(s - LAG_) * B_ * D_,
            wihHi + (1 << 22), wihLo + (1 << 22), b_ih + FH_, P1, D_, FH_);
      }
    }
    prm.s = s;
    prm.tgt = 256u * (unsigned)(s + 1);
    void* args[] = { &prm };
    hipLaunchCooperativeKernel(reinterpret_cast<void*>(fused_step_k),
                               dim3(256), dim3(512), args, SMEM_TOTAL, stream);
  }

  // --- final FC: out[b][t][c] = Y1[t*B+b,:]·fc_w[c,:] + fc_b ---
  gemm3_k<1><<<dim3(H_ / 128, (T_ * B_) / 128), 256, 0, stream>>>(
      XYhi, XYlo, fcHi, fcLo, fc_b, out, H_, H_);
}

// Round 9
// 33972.266 us; speedup vs baseline: 1.3449x; 1.3449x over previous
//
#include <hip/hip_runtime.h>

// ---------------------------------------------------------------------------
// LayerNorm-LSTM (depth=2) + FC, MI355X. Split-bf16 (hi/lo) 3-term MFMA.
// Round 9: "span" kernels — each regular launch runs 16 recurrence steps with
// Whh (hi+lo, fragment-order) resident in 128KB LDS; cross-block sync via a
// contention-free monotonic flag-array barrier (store + wave-min spin).
// Chunk ih-projections + FC remain separate full-occupancy GEMM launches.
// ---------------------------------------------------------------------------

typedef __attribute__((ext_vector_type(8))) short short8;
typedef __attribute__((ext_vector_type(8))) __bf16 bf16x8;
typedef __attribute__((ext_vector_type(4))) float f32x4;
typedef __attribute__((ext_vector_type(4))) unsigned short us4;

#define B_ 64
#define T_ 512
#define D_ 1024
#define H_ 1024
#define FH_ 4096
#define LAG_ 16
#define NSPAN 16
#define SPANS 33               // 33*16 = 528 = T + LAG
#define RCH_ (B_ * 16)         // 1024 rows per chunk window

#define SMEM_WHH 131072        // dynamic LDS: Whh hi+lo fragment slice

typedef const __attribute__((address_space(1))) unsigned int* gas_ptr;
typedef __attribute__((address_space(3))) unsigned int* las_ptr;
#define GLOAD_LDS16(g, l) \
  __builtin_amdgcn_global_load_lds((gas_ptr)(g), (las_ptr)(l), 16, 0, 0)

static __device__ __forceinline__ unsigned short f2bf(float f) {
  unsigned int u = __builtin_bit_cast(unsigned int, f);
  u += 0x7FFFu + ((u >> 16) & 1u);   // round-to-nearest-even
  return (unsigned short)(u >> 16);
}
static __device__ __forceinline__ float bf2f(unsigned short u) {
  unsigned int x = ((unsigned int)u) << 16;
  return __builtin_bit_cast(float, x);
}

// ---------------- split-cast fp32 -> (hi, lo) bf16 ----------------
__global__ void cast_split_k(const float4* __restrict__ in,
                             us4* __restrict__ hi, us4* __restrict__ lo, int n4) {
  int i = blockIdx.x * 256 + threadIdx.x;
  if (i < n4) {
    float4 v = in[i];
    us4 h, l;
    h[0] = f2bf(v.x); l[0] = f2bf(v.x - bf2f(h[0]));
    h[1] = f2bf(v.y); l[1] = f2bf(v.y - bf2f(h[1]));
    h[2] = f2bf(v.z); l[2] = f2bf(v.z - bf2f(h[2]));
    h[3] = f2bf(v.w); l[3] = f2bf(v.w - bf2f(h[3]));
    hi[i] = h; lo[i] = l;
  }
}

// ------ transpose-split input [B][T][D] f32 -> [T][B][D] (hi, lo) bf16 -----
__global__ void transpose_split_k(const float4* __restrict__ x,
                                  us4* __restrict__ hi, us4* __restrict__ lo) {
  int i = blockIdx.x * 256 + threadIdx.x;
  int d4  = i & 255;
  int rem = i >> 8;
  int b = rem & 63;
  int t = rem >> 6;
  float4 v = x[((size_t)(b * T_ + t) << 8) + d4];
  us4 h, l;
  h[0] = f2bf(v.x); l[0] = f2bf(v.x - bf2f(h[0]));
  h[1] = f2bf(v.y); l[1] = f2bf(v.y - bf2f(h[1]));
  h[2] = f2bf(v.z); l[2] = f2bf(v.z - bf2f(h[2]));
  h[3] = f2bf(v.w); l[3] = f2bf(v.w - bf2f(h[3]));
  size_t o = ((size_t)(t * B_ + b) << 8) + d4;
  hi[o] = h; lo[o] = l;
}

// ------ fragment-ordered Whh (hi then lo halves), R4-proven layout ---------
// 16B chunk i: b=i>>13 (block slice; layer=b>>7, colbase=(b&127)*32),
// sel=(i>>12)&1, g=(i>>11)&1, kc=(i>>6)&31, lane=i&63.
// col = colbase + g*16 + (lane&15); kof = kc*32 + (lane>>4)*8.
__global__ void whh_frag_k(const float* __restrict__ w_hh,
                           unsigned short* __restrict__ frag) {
  int i = blockIdx.x * 256 + threadIdx.x;    // 2,097,152 chunks
  int b    = i >> 13;
  int rem  = i & 8191;
  int sel  = rem >> 12;
  int rem2 = rem & 4095;
  int g    = rem2 >> 11;
  int rem3 = rem2 & 2047;
  int kc   = rem3 >> 6;
  int lane = rem3 & 63;
  int layer = b >> 7;
  int col = (b & 127) * 32 + g * 16 + (lane & 15);
  int kof = kc * 32 + (lane >> 4) * 8;
  const float* src = w_hh + ((size_t)layer * FH_ + col) * 1024 + kof;
  short8 o;
#pragma unroll
  for (int e = 0; e < 8; ++e) {
    float v = src[e];
    unsigned short h = f2bf(v);
    o[e] = sel ? (short)f2bf(v - bf2f(h)) : (short)h;
  }
  *(short8*)(frag + (size_t)i * 8) = o;
}

// ---------------- 3-term split-bf16 GEMM (chunk projections + FC) ----------
template <int FCMODE>
__global__ __launch_bounds__(256) void gemm3_k(
    const unsigned short* __restrict__ Ahi, const unsigned short* __restrict__ Alo,
    const unsigned short* __restrict__ Whi, const unsigned short* __restrict__ Wlo,
    const float* __restrict__ bias, float* __restrict__ out, int K, int N) {
  __shared__ unsigned short lAh[128 * 40];
  __shared__ unsigned short lAl[128 * 40];
  __shared__ unsigned short lWh[128 * 40];
  __shared__ unsigned short lWl[128 * 40];
  int tid = threadIdx.x;
  int l = tid & 63, w = tid >> 6;
  int r0 = blockIdx.y * 128, c0 = blockIdx.x * 128;
  int wr = (w >> 1) * 64, wc = (w & 1) * 64;
  int lr = l & 15, lk = (l >> 4) * 8;
  f32x4 acc[4][4] = {};
  int srow = tid >> 2;
  int scc  = (tid & 3) * 8;

  for (int kt = 0; kt < K; kt += 32) {
#pragma unroll
    for (int i = 0; i < 2; ++i) {
      int row = srow + i * 64;
      size_t aoff = (size_t)(r0 + row) * K + kt + scc;
      size_t woff = (size_t)(c0 + row) * K + kt + scc;
      *(short8*)&lAh[row * 40 + scc] = *(const short8*)(Ahi + aoff);
      *(short8*)&lAl[row * 40 + scc] = *(const short8*)(Alo + aoff);
      *(short8*)&lWh[row * 40 + scc] = *(const short8*)(Whi + woff);
      *(short8*)&lWl[row * 40 + scc] = *(const short8*)(Wlo + woff);
    }
    __syncthreads();
    bf16x8 ah[4], al[4], bh[4], bl[4];
#pragma unroll
    for (int mi = 0; mi < 4; ++mi) {
      ah[mi] = *(bf16x8*)&lAh[(wr + mi * 16 + lr) * 40 + lk];
      al[mi] = *(bf16x8*)&lAl[(wr + mi * 16 + lr) * 40 + lk];
    }
#pragma unroll
    for (int ni = 0; ni < 4; ++ni) {
      bh[ni] = *(bf16x8*)&lWh[(wc + ni * 16 + lr) * 40 + lk];
      bl[ni] = *(bf16x8*)&lWl[(wc + ni * 16 + lr) * 40 + lk];
    }
#pragma unroll
    for (int mi = 0; mi < 4; ++mi)
#pragma unroll
      for (int ni = 0; ni < 4; ++ni) {
        acc[mi][ni] = __builtin_amdgcn_mfma_f32_16x16x32_bf16(ah[mi], bh[ni], acc[mi][ni], 0, 0, 0);
        acc[mi][ni] = __builtin_amdgcn_mfma_f32_16x16x32_bf16(ah[mi], bl[ni], acc[mi][ni], 0, 0, 0);
        acc[mi][ni] = __builtin_amdgcn_mfma_f32_16x16x32_bf16(al[mi], bh[ni], acc[mi][ni], 0, 0, 0);
      }
    __syncthreads();
  }

#pragma unroll
  for (int mi = 0; mi < 4; ++mi)
#pragma unroll
    for (int ni = 0; ni < 4; ++ni)
#pragma unroll
      for (int reg = 0; reg < 4; ++reg) {
        int r = r0 + wr + mi * 16 + (l >> 4) * 4 + reg;
        int c = c0 + wc + ni * 16 + lr;
        float v = acc[mi][ni][reg] + bias[c];
        if (FCMODE) {
          int b = r & 63, t = r >> 6;
          out[((size_t)b * T_ + t) * (size_t)N + c] = v;
        } else {
          out[(size_t)r * N + c] = v;
        }
      }
}

// ---------------- span kernel: 16 recurrence steps per launch --------------
struct SpanP {
  const unsigned short* whhF;
  const float *P0, *P1;
  unsigned short *hH, *hL, *XYhi, *XYlo;
  float *cst, *G;
  const float *bhh, *gih, *beih, *ghh, *behh, *gho, *beho;
  unsigned* flags;
  int s0; unsigned ep0;
};

// contention-free monotonic grid barrier: store own flag, wave-min spin.
static __device__ __forceinline__ void flagbar(unsigned* flags, unsigned ep,
                                               int tid, unsigned* bmin) {
  __syncthreads();                     // all waves' stores drained to L2
  if (tid == 0) {
    __threadfence();                   // release: wb L2 -> L3
    __hip_atomic_store(&flags[blockIdx.x], ep, __ATOMIC_RELAXED,
                       __HIP_MEMORY_SCOPE_AGENT);
  }
  const int w = tid >> 6, l = tid & 63;
  for (;;) {
    unsigned v = __hip_atomic_load(&flags[((w & 3) << 6) | l], __ATOMIC_RELAXED,
                                   __HIP_MEMORY_SCOPE_AGENT);
#pragma unroll
    for (int o = 32; o; o >>= 1) {
      unsigned u = (unsigned)__shfl_xor((int)v, o);
      v = v < u ? v : u;
    }
    if (l == 0) bmin[w] = v;
    __syncthreads();
    unsigned m = bmin[0];
#pragma unroll
    for (int k = 1; k < 8; ++k) { unsigned u = bmin[k]; m = m < u ? m : u; }
    if (m >= ep) break;
    __syncthreads();
    __builtin_amdgcn_s_sleep(4);
  }
  if (tid == 0) __threadfence();       // acquire: invalidate L1/L2
  __syncthreads();
}

__global__ __launch_bounds__(512) void span_k(SpanP p) {
  extern __shared__ char smem[];
  unsigned short* wl = (unsigned short*)smem;   // 128KB Whh hi+lo frag slice
  __shared__ float red[32];
  __shared__ unsigned bmin[8];

  const int tid = threadIdx.x;
  const int blk = blockIdx.x;
  const int w = tid >> 6, l = tid & 63;
  const int lr = l & 15, lq = l >> 4;

  // ---- span prologue: stage this block's Whh frag slice (once) ----
  {
    const unsigned short* gsrc = p.whhF + ((size_t)blk << 16);
#pragma unroll
    for (int r = 0; r < 16; ++r) {
      int c = r * 512 + tid;
      GLOAD_LDS16(gsrc + (size_t)c * 8, wl + (size_t)c * 8);
    }
    __syncthreads();   // drains vmcnt
  }

  // ---- c-state in registers for the whole span (pointwise blocks) ----
  const int pw_layer = blk >> 6;       // valid for blk<128
  const int pw_r = blk & 63;
  float creg[2] = {0.0f, 0.0f};
  if (blk < 128) {
#pragma unroll
    for (int u = 0; u < 2; ++u)
      creg[u] = p.cst[((size_t)(pw_layer * B_ + pw_r)) * H_ + tid + 512 * u];
  }

  unsigned ep = p.ep0;
  for (int sl = 0; sl < NSPAN; ++sl) {
    int s = p.s0 + sl;

    // ================= hh GEMM phase (Whh from LDS) =================
    {
      int layer = blk >> 7;
      int t0 = layer ? (s - LAG_) : s;
      if (t0 >= 0 && t0 < T_) {
        int jb = blk & 127;
        int cf = w >> 2;                   // colfrag 0..1
        int m0 = (w & 3) * 16;             // rowfrag base
        const unsigned short* hHb = p.hH + layer * 65536;
        const unsigned short* hLb = p.hL + layer * 65536;
        const short8* wfrag = (const short8*)wl;
        f32x4 acc = {};
#pragma unroll 8
        for (int kc = 0; kc < 32; ++kc) {
          int k = kc * 32 + lq * 8;
          bf16x8 ah = __builtin_bit_cast(bf16x8, *(const short8*)(hHb + (m0 + lr) * 1024 + k));
          bf16x8 al = __builtin_bit_cast(bf16x8, *(const short8*)(hLb + (m0 + lr) * 1024 + k));
          bf16x8 bh = __builtin_bit_cast(bf16x8, wfrag[(cf * 32 + kc) * 64 + l]);
          bf16x8 bl = __builtin_bit_cast(bf16x8, wfrag[4096 + (cf * 32 + kc) * 64 + l]);
          acc = __builtin_amdgcn_mfma_f32_16x16x32_bf16(ah, bh, acc, 0, 0, 0);
          acc = __builtin_amdgcn_mfma_f32_16x16x32_bf16(al, bh, acc, 0, 0, 0);
          acc = __builtin_amdgcn_mfma_f32_16x16x32_bf16(ah, bl, acc, 0, 0, 0);
        }
        float* Gb = p.G + layer * (64 * FH_);
        int n0 = jb * 32 + cf * 16;
#pragma unroll
        for (int reg = 0; reg < 4; ++reg) {
          int row = m0 + lq * 4 + reg;
          Gb[(size_t)row * FH_ + n0 + lr] = acc[reg];
        }
      }
    }
    ++ep; flagbar(p.flags, ep, tid, bmin);

    // ================= pointwise phase =================
    if (blk < 128) {
      int layer = pw_layer;
      int t0 = layer ? (s - LAG_) : s;
      if (t0 >= 0 && t0 < T_) {
        int r = pw_r;
        int slot = s & 15;
        const float* Pr = (layer ? p.P1 : p.P0) + ((size_t)slot * B_ + r) * FH_;
        const float* Gr = p.G + layer * (64 * FH_) + (size_t)r * FH_;
        const float* bhh = p.bhh + layer * FH_;
        const float* gih = p.gih + layer * FH_;
        const float* beih= p.beih + layer * FH_;
        const float* ghh = p.ghh + layer * FH_;
        const float* behh= p.behh + layer * FH_;
        const float* gho = p.gho + layer * H_;
        const float* beho= p.beho + layer * H_;
        int wv = tid >> 6, ln = tid & 63;

        float ihp[8], hhp[8];
        float s1 = 0, q1 = 0, s2 = 0, q2 = 0;
#pragma unroll
        for (int st = 0; st < 8; ++st) {
          int n = tid + 512 * st;
          float a = Pr[n];
          float b = Gr[n] + bhh[n];
          ihp[st] = a; hhp[st] = b;
          s1 += a; q1 += a * a; s2 += b; q2 += b * b;
        }
#pragma unroll
        for (int o = 32; o; o >>= 1) {
          s1 += __shfl_down(s1, o); q1 += __shfl_down(q1, o);
          s2 += __shfl_down(s2, o); q2 += __shfl_down(q2, o);
        }
        if (ln == 0) { red[wv*4] = s1; red[wv*4+1] = q1; red[wv*4+2] = s2; red[wv*4+3] = q2; }
        __syncthreads();
        s1 = 0; q1 = 0; s2 = 0; q2 = 0;
#pragma unroll
        for (int k = 0; k < 8; ++k) {
          s1 += red[k*4]; q1 += red[k*4+1]; s2 += red[k*4+2]; q2 += red[k*4+3];
        }
        __syncthreads();

        const float inv4h = 1.0f / 4096.0f;
        float m1 = s1 * inv4h, m2 = s2 * inv4h;
        float i1 = rsqrtf(q1 * inv4h - m1 * m1 + 1e-5f);
        float i2 = rsqrtf(q2 * inv4h - m2 * m2 + 1e-5f);

        float pre[8];
#pragma unroll
        for (int st = 0; st < 8; ++st) {
          int n = tid + 512 * st;
          pre[st] = gih[n] * (ihp[st] - m1) * i1 + beih[n] + ghh[n] * (hhp[st] - m2) * i2 + behh[n];
        }

        float cn[2], og[2];
        float s3 = 0, q3 = 0;
#pragma unroll
        for (int u = 0; u < 2; ++u) {
          float iG = 1.0f / (1.0f + __expf(-pre[u]));
          float fG = 1.0f / (1.0f + __expf(-pre[2 + u]));
          float oG = 1.0f / (1.0f + __expf(-pre[4 + u]));
          float gG = tanhf(pre[6 + u]);
          float c = fG * creg[u] + iG * gG;
          creg[u] = c;
          cn[u] = c; og[u] = oG;
          s3 += c; q3 += c * c;
        }
#pragma unroll
        for (int o = 32; o; o >>= 1) { s3 += __shfl_down(s3, o); q3 += __shfl_down(q3, o); }
        if (ln == 0) { red[wv*4] = s3; red[wv*4+1] = q3; }
        __syncthreads();
        s3 = 0; q3 = 0;
#pragma unroll
        for (int k = 0; k < 8; ++k) { s3 += red[k*4]; q3 += red[k*4+1]; }

        const float invh = 1.0f / 1024.0f;
        float m3 = s3 * invh;
        float i3 = rsqrtf(q3 * invh - m3 * m3 + 1e-5f);
        unsigned short* hHb = p.hH + layer * 65536 + (size_t)r * H_;
        unsigned short* hLb = p.hL + layer * 65536 + (size_t)r * H_;
        unsigned short* YH = p.XYhi + ((size_t)t0 * B_ + r) * H_;
        unsigned short* YL = p.XYlo + ((size_t)t0 * B_ + r) * H_;
#pragma unroll
        for (int u = 0; u < 2; ++u) {
          int hidx = tid + 512 * u;
          float hy = og[u] * tanhf((cn[u] - m3) * i3 * gho[hidx] + beho[hidx]);
          unsigned short hv = f2bf(hy);
          unsigned short lv = f2bf(hy - bf2f(hv));
          hHb[hidx] = hv; hLb[hidx] = lv;
          YH[hidx] = hv;  YL[hidx] = lv;
        }
      }
    }
    if (sl < NSPAN - 1) { ++ep; flagbar(p.flags, ep, tid, bmin); }
  }

  // ---- span epilogue: persist c-state ----
  if (blk < 128) {
#pragma unroll
    for (int u = 0; u < 2; ++u)
      p.cst[((size_t)(pw_layer * B_ + pw_r)) * H_ + tid + 512 * u] = creg[u];
  }
}

// ---------------------------------------------------------------------------
extern "C" void kernel_launch(void* const* d_in, const int* in_sizes, int n_in,
                              void* d_out, int out_size, void* d_ws, size_t ws_size,
                              hipStream_t stream) {
  const float* x    = (const float*)d_in[0];
  const float* w_ih = (const float*)d_in[1];
  const float* b_ih = (const float*)d_in[2];
  const float* w_hh = (const float*)d_in[3];
  const float* b_hh = (const float*)d_in[4];
  const float* g_ih = (const float*)d_in[5];
  const float* be_ih= (const float*)d_in[6];
  const float* g_hh = (const float*)d_in[7];
  const float* be_hh= (const float*)d_in[8];
  const float* g_ho = (const float*)d_in[9];
  const float* be_ho= (const float*)d_in[10];
  const float* fc_w = (const float*)d_in[11];
  const float* fc_b = (const float*)d_in[12];
  float* out = (float*)d_out;
  (void)ws_size; (void)in_sizes; (void)n_in; (void)out_size;

  // workspace carve-up (~231 MB)
  char* wsb = (char*)d_ws;
  size_t off = 0;
  unsigned short* wihHi  = (unsigned short*)(wsb + off); off += 16777216;
  unsigned short* wihLo  = (unsigned short*)(wsb + off); off += 16777216;
  unsigned short* whhF   = (unsigned short*)(wsb + off); off += 33554432;  // hi+lo frag
  unsigned short* fcHi   = (unsigned short*)(wsb + off); off += 2097152;
  unsigned short* fcLo   = (unsigned short*)(wsb + off); off += 2097152;
  unsigned short* XYhi   = (unsigned short*)(wsb + off); off += 67108864;  // [T][64][1024] X->Y0->Y1
  unsigned short* XYlo   = (unsigned short*)(wsb + off); off += 67108864;
  float* P0              = (float*)(wsb + off); off += (size_t)16 * B_ * FH_ * 4; // 16 MB
  float* P1              = (float*)(wsb + off); off += (size_t)16 * B_ * FH_ * 4; // 16 MB
  float* G               = (float*)(wsb + off); off += (size_t)2 * B_ * FH_ * 4;  // 2 MB
  unsigned short* hH     = (unsigned short*)(wsb + off); off += 262144;
  unsigned short* hL     = (unsigned short*)(wsb + off); off += 262144;
  float* cst             = (float*)(wsb + off); off += 524288;
  unsigned* flags        = (unsigned*)(wsb + off); off += 1024;

  // --- weight prep ---
  {
    int n4 = 2 * FH_ * D_ / 4;
    cast_split_k<<<(n4 + 255) / 256, 256, 0, stream>>>((const float4*)w_ih, (us4*)wihHi, (us4*)wihLo, n4);
    int nf = H_ * H_ / 4;
    cast_split_k<<<(nf + 255) / 256, 256, 0, stream>>>((const float4*)fc_w, (us4*)fcHi, (us4*)fcLo, nf);
    int nx = T_ * B_ * D_ / 4;
    transpose_split_k<<<nx / 256, 256, 0, stream>>>((const float4*)x, (us4*)XYhi, (us4*)XYlo);
    whh_frag_k<<<8192, 256, 0, stream>>>(w_hh, whhF);
  }

  // --- state init (graph nodes; re-run each replay) ---
  hipMemsetAsync(hH, 0, 262144, stream);
  hipMemsetAsync(hL, 0, 262144, stream);
  hipMemsetAsync(cst, 0, 524288, stream);
  hipMemsetAsync(flags, 0, 1024, stream);

  hipFuncSetAttribute(reinterpret_cast<const void*>(span_k),
                      hipFuncAttributeMaxDynamicSharedMemorySize, SMEM_WHH);

  // --- recurrence: 33 span launches, chunk GEMMs interleaved ---
  SpanP prm;
  prm.whhF = whhF; prm.P0 = P0; prm.P1 = P1;
  prm.hH = hH; prm.hL = hL; prm.XYhi = XYhi; prm.XYlo = XYlo;
  prm.cst = cst; prm.G = G;
  prm.bhh = b_hh; prm.gih = g_ih; prm.beih = be_ih;
  prm.ghh = g_hh; prm.behh = be_hh; prm.gho = g_ho; prm.beho = be_ho;
  prm.flags = flags;

  for (int c = 0; c < SPANS; ++c) {
    int s = c * NSPAN;
    if (s < T_) {
      gemm3_k<0><<<dim3(FH_ / 128, RCH_ / 128), 256, 0, stream>>>(
          XYhi + (size_t)s * B_ * D_, XYlo + (size_t)s * B_ * D_,
          wihHi, wihLo, b_ih, P0, D_, FH_);
    }
    if (s >= LAG_) {
      gemm3_k<0><<<dim3(FH_ / 128, RCH_ / 128), 256, 0, stream>>>(
          XYhi + (size_t)(s - LAG_) * B_ * D_, XYlo + (size_t)(s - LAG_) * B_ * D_,
          wihHi + (1 << 22), wihLo + (1 << 22), b_ih + FH_, P1, D_, FH_);
    }
    prm.s0 = s;
    prm.ep0 = (unsigned)c * 31u;
    span_k<<<256, 512, SMEM_WHH, stream>>>(prm);
  }

  // --- final FC: out[b][t][c] = Y1[t*B+b,:]·fc_w[c,:] + fc_b ---
  gemm3_k<1><<<dim3(H_ / 128, (T_ * B_) / 128), 256, 0, stream>>>(
      XYhi, XYlo, fcHi, fcLo, fc_b, out, H_, H_);
}

// Round 10
// 25449.846 us; speedup vs baseline: 1.7953x; 1.3349x over previous
//
#include <hip/hip_runtime.h>

// ---------------------------------------------------------------------------
// LayerNorm-LSTM (depth=2) + FC, MI355X. Split-bf16 (hi/lo) 3-term MFMA.
// Round 10: fence-free span kernel. 33 regular launches x 16 steps. Whh hi+lo
// resident in 128KB LDS (R8's gate-interleaved fragment layout). Per step:
//   A: hh MFMA -> gate strip in LDS (+bias), LN1 partial stats (sc1 stores)
//   B: 128 summer blocks reduce partials -> stats1
//   C: LN1 + gates + cell update (c in regs), cell partial stats
//   D: summers -> stats2
//   E: cell-LN + h (pair-packed sc1 u32, 16 rotating slots) + Y
// Sync = monotonic flag arrays (agent-scope atomics), NO threadfence ever.
// ---------------------------------------------------------------------------

typedef __attribute__((ext_vector_type(8))) short short8;
typedef __attribute__((ext_vector_type(8))) __bf16 bf16x8;
typedef __attribute__((ext_vector_type(4))) float f32x4;
typedef __attribute__((ext_vector_type(4))) unsigned short us4;

#define B_ 64
#define T_ 512
#define D_ 1024
#define H_ 1024
#define FH_ 4096
#define LAG_ 16
#define NSPAN 16
#define SPANS 33               // 33*16 = 528 = T + LAG
#define RCH_ (B_ * 16)

#define SMEM_WHH 131072
#define SMEM_TOTAL (SMEM_WHH + 64 * 33 * 4)   // + ldshh [64][33] f32

typedef const __attribute__((address_space(1))) unsigned int* gas_ptr;
typedef __attribute__((address_space(3))) unsigned int* las_ptr;
#define GLOAD_LDS16(g, l) \
  __builtin_amdgcn_global_load_lds((gas_ptr)(g), (las_ptr)(l), 16, 0, 0)

#define ALD(p)    __hip_atomic_load((p), __ATOMIC_RELAXED, __HIP_MEMORY_SCOPE_AGENT)
#define AST(p, v) __hip_atomic_store((p), (v), __ATOMIC_RELAXED, __HIP_MEMORY_SCOPE_AGENT)

static __device__ __forceinline__ unsigned short f2bf(float f) {
  unsigned int u = __builtin_bit_cast(unsigned int, f);
  u += 0x7FFFu + ((u >> 16) & 1u);   // round-to-nearest-even
  return (unsigned short)(u >> 16);
}
static __device__ __forceinline__ float bf2f(unsigned short u) {
  unsigned int x = ((unsigned int)u) << 16;
  return __builtin_bit_cast(float, x);
}

// ---------------- split-cast fp32 -> (hi, lo) bf16 ----------------
__global__ void cast_split_k(const float4* __restrict__ in,
                             us4* __restrict__ hi, us4* __restrict__ lo, int n4) {
  int i = blockIdx.x * 256 + threadIdx.x;
  if (i < n4) {
    float4 v = in[i];
    us4 h, l;
    h[0] = f2bf(v.x); l[0] = f2bf(v.x - bf2f(h[0]));
    h[1] = f2bf(v.y); l[1] = f2bf(v.y - bf2f(h[1]));
    h[2] = f2bf(v.z); l[2] = f2bf(v.z - bf2f(h[2]));
    h[3] = f2bf(v.w); l[3] = f2bf(v.w - bf2f(h[3]));
    hi[i] = h; lo[i] = l;
  }
}

// ------ transpose-split input [B][T][D] f32 -> [T][B][D] (hi, lo) bf16 -----
__global__ void transpose_split_k(const float4* __restrict__ x,
                                  us4* __restrict__ hi, us4* __restrict__ lo) {
  int i = blockIdx.x * 256 + threadIdx.x;
  int d4  = i & 255;
  int rem = i >> 8;
  int b = rem & 63;
  int t = rem >> 6;
  float4 v = x[((size_t)(b * T_ + t) << 8) + d4];
  us4 h, l;
  h[0] = f2bf(v.x); l[0] = f2bf(v.x - bf2f(h[0]));
  h[1] = f2bf(v.y); l[1] = f2bf(v.y - bf2f(h[1]));
  h[2] = f2bf(v.z); l[2] = f2bf(v.z - bf2f(h[2]));
  h[3] = f2bf(v.w); l[3] = f2bf(v.w - bf2f(h[3]));
  size_t o = ((size_t)(t * B_ + b) << 8) + d4;
  hi[o] = h; lo[o] = l;
}

// ------ fragment-ordered Whh (hi AND lo), gate-interleaved (R8-proven) -----
__global__ void whh_frag3_k(const float* __restrict__ w_hh,
                            unsigned short* __restrict__ frag) {
  int i = blockIdx.x * 256 + threadIdx.x;    // 2,097,152 chunks
  int lane = i & 63;
  int kc   = (i >> 6) & 31;
  int g    = (i >> 11) & 1;
  int sel  = (i >> 12) & 1;
  int j    = (i >> 13) & 127;
  int layer= (i >> 20) & 1;
  int fc = lane & 15;
  int gc = (g * 2 + (fc >> 3)) * 1024 + j * 8 + (fc & 7);
  int k0 = kc * 32 + (lane >> 4) * 8;
  const float* src = w_hh + ((size_t)layer * FH_ + gc) * 1024 + k0;
  short8 o;
#pragma unroll
  for (int e = 0; e < 8; ++e) {
    float v = src[e];
    unsigned short h = f2bf(v);
    o[e] = sel ? (short)f2bf(v - bf2f(h)) : (short)h;
  }
  *(short8*)(frag + (size_t)i * 8) = o;
}

// ---------------- 3-term split-bf16 GEMM (chunk projections + FC) ----------
template <int FCMODE>
__global__ __launch_bounds__(256) void gemm3_k(
    const unsigned short* __restrict__ Ahi, const unsigned short* __restrict__ Alo,
    const unsigned short* __restrict__ Whi, const unsigned short* __restrict__ Wlo,
    const float* __restrict__ bias, float* __restrict__ out, int K, int N) {
  __shared__ unsigned short lAh[128 * 40];
  __shared__ unsigned short lAl[128 * 40];
  __shared__ unsigned short lWh[128 * 40];
  __shared__ unsigned short lWl[128 * 40];
  int tid = threadIdx.x;
  int l = tid & 63, w = tid >> 6;
  int r0 = blockIdx.y * 128, c0 = blockIdx.x * 128;
  int wr = (w >> 1) * 64, wc = (w & 1) * 64;
  int lr = l & 15, lk = (l >> 4) * 8;
  f32x4 acc[4][4] = {};
  int srow = tid >> 2;
  int scc  = (tid & 3) * 8;

  for (int kt = 0; kt < K; kt += 32) {
#pragma unroll
    for (int i = 0; i < 2; ++i) {
      int row = srow + i * 64;
      size_t aoff = (size_t)(r0 + row) * K + kt + scc;
      size_t woff = (size_t)(c0 + row) * K + kt + scc;
      *(short8*)&lAh[row * 40 + scc] = *(const short8*)(Ahi + aoff);
      *(short8*)&lAl[row * 40 + scc] = *(const short8*)(Alo + aoff);
      *(short8*)&lWh[row * 40 + scc] = *(const short8*)(Whi + woff);
      *(short8*)&lWl[row * 40 + scc] = *(const short8*)(Wlo + woff);
    }
    __syncthreads();
    bf16x8 ah[4], al[4], bh[4], bl[4];
#pragma unroll
    for (int mi = 0; mi < 4; ++mi) {
      ah[mi] = *(bf16x8*)&lAh[(wr + mi * 16 + lr) * 40 + lk];
      al[mi] = *(bf16x8*)&lAl[(wr + mi * 16 + lr) * 40 + lk];
    }
#pragma unroll
    for (int ni = 0; ni < 4; ++ni) {
      bh[ni] = *(bf16x8*)&lWh[(wc + ni * 16 + lr) * 40 + lk];
      bl[ni] = *(bf16x8*)&lWl[(wc + ni * 16 + lr) * 40 + lk];
    }
#pragma unroll
    for (int mi = 0; mi < 4; ++mi)
#pragma unroll
      for (int ni = 0; ni < 4; ++ni) {
        acc[mi][ni] = __builtin_amdgcn_mfma_f32_16x16x32_bf16(ah[mi], bh[ni], acc[mi][ni], 0, 0, 0);
        acc[mi][ni] = __builtin_amdgcn_mfma_f32_16x16x32_bf16(ah[mi], bl[ni], acc[mi][ni], 0, 0, 0);
        acc[mi][ni] = __builtin_amdgcn_mfma_f32_16x16x32_bf16(al[mi], bh[ni], acc[mi][ni], 0, 0, 0);
      }
    __syncthreads();
  }

#pragma unroll
  for (int mi = 0; mi < 4; ++mi)
#pragma unroll
    for (int ni = 0; ni < 4; ++ni)
#pragma unroll
      for (int reg = 0; reg < 4; ++reg) {
        int r = r0 + wr + mi * 16 + (l >> 4) * 4 + reg;
        int c = c0 + wc + ni * 16 + lr;
        float v = acc[mi][ni][reg] + bias[c];
        if (FCMODE) {
          int b = r & 63, t = r >> 6;
          out[((size_t)b * T_ + t) * (size_t)N + c] = v;
        } else {
          out[(size_t)r * N + c] = v;
        }
      }
}

// ---------------- span kernel ----------------
struct SpanP {
  const unsigned short* whhF;
  const float *P0, *P1;
  unsigned short *hpHi, *hpLo;     // [16 slot][2 layer][64][1024] ushort
  unsigned short *XYhi, *XYlo;
  float* cst;                      // [2][64][1024]
  const float *bhh, *gih, *beih, *ghh, *behh, *gho, *beho;
  float *part1, *part2;            // [2][64][4][128] / [2][64][2][128]
  float *stats1, *stats2;          // [2][64][4] / [2][64][2]
  unsigned *f1, *f2, *f3, *f4, *fE;
  int s0;
};

// fence-free flag wait: min over f[base .. base+cntm+1) >= ep
static __device__ __forceinline__ void waitf(const unsigned* f, int base, int cntm,
                                             unsigned ep, unsigned* bmin) {
  const int tid = threadIdx.x;
  const unsigned* addr = f + base + (tid & cntm);
  for (;;) {
    unsigned v = ALD(addr);
#pragma unroll
    for (int o = 32; o; o >>= 1) {
      unsigned u = (unsigned)__shfl_xor((int)v, o);
      v = v < u ? v : u;
    }
    if ((tid & 63) == 0) bmin[tid >> 6] = v;
    __syncthreads();
    unsigned m = bmin[0];
#pragma unroll
    for (int k = 1; k < 8; ++k) { unsigned u = bmin[k]; m = m < u ? m : u; }
    __syncthreads();
    if (m >= ep) return;
    __builtin_amdgcn_s_sleep(2);
  }
}

__global__ __launch_bounds__(512) void span_k(SpanP p) {
  extern __shared__ char smem[];
  unsigned short* wl = (unsigned short*)smem;          // 128KB Whh hi+lo frags
  float* ldshh = (float*)(smem + SMEM_WHH);            // [64][33]
  __shared__ unsigned bmin[8];
  __shared__ float red8[8];

  const int tid = threadIdx.x;
  const int blk = blockIdx.x;
  const int layer = blk >> 7;        // hh-role layer
  const int j = blk & 127;
  const int w = tid >> 6, l = tid & 63;
  const int lr = l & 15, lq = l >> 4;
  const int slayer = blk >> 6;       // summer-role layer (blk<128)
  const int srow = blk & 63;         // summer-role row

  // ---- span prologue: stage Whh hi+lo frag slice (once) ----
  {
    const unsigned short* gsrc = p.whhF + ((size_t)blk << 16);
#pragma unroll
    for (int r = 0; r < 16; ++r) {
      int c = r * 512 + tid;
      GLOAD_LDS16(gsrc + (size_t)c * 8, wl + (size_t)c * 8);
    }
  }

  // pointwise identity of this thread within the block's strip
  const int row = tid >> 3, c8 = tid & 7;
  const int hcol = j * 8 + c8;
  float creg = p.cst[((size_t)(layer * B_ + row)) * H_ + hcol];

  __syncthreads();   // staging complete (vmcnt drained)

  for (int sl = 0; sl < NSPAN; ++sl) {
    const int s = p.s0 + sl;
    const unsigned g = (unsigned)(s + 1);
    const int t0 = layer ? (s - LAG_) : s;
    const bool active = (t0 >= 0) && (t0 < T_);
    const int slotp = (sl - 1) & 15;   // h slot of previous step
    const int slot = sl;

    // ================= phase A: hh MFMA + strip + LN1 partials =============
    waitf(p.fE, layer * 128, 127, g - 1, bmin);
    float ih[4], hh[4];
    if (active) {
      // early P loads
      const float* Pb = layer ? p.P1 : p.P0;
      int ps = s & 15;
#pragma unroll
      for (int q = 0; q < 4; ++q)
        ih[q] = Pb[((size_t)(ps * B_ + row)) * FH_ + q * 1024 + hcol];

      // hh MFMA: wave w -> rowfrag rf=w>>1, colgroup gch=w&1
      const int rf = w >> 1, gch = w & 1;
      const int rowbase = rf * 16;
      const int fc = lr;
      const int q4 = gch * 2 + (fc >> 3);
      const int gc = q4 * 1024 + j * 8 + (fc & 7);
      const unsigned short* hHb = p.hpHi + ((size_t)(slotp * 2 + layer)) * 65536;
      const unsigned short* hLb = p.hpLo + ((size_t)(slotp * 2 + layer)) * 65536;
      f32x4 acc = {};
#pragma unroll 8
      for (int kc = 0; kc < 32; ++kc) {
        int k = kc * 32 + lq * 8;
        bf16x8 ah = __builtin_bit_cast(bf16x8, *(const short8*)(hHb + (rowbase + lr) * 1024 + k));
        bf16x8 al = __builtin_bit_cast(bf16x8, *(const short8*)(hLb + (rowbase + lr) * 1024 + k));
        bf16x8 bh = __builtin_bit_cast(bf16x8, *(const short8*)&wl[(size_t)(gch * 2048 + kc * 64 + l) * 8]);
        bf16x8 bl = __builtin_bit_cast(bf16x8, *(const short8*)&wl[(size_t)(4096 + gch * 2048 + kc * 64 + l) * 8]);
        acc = __builtin_amdgcn_mfma_f32_16x16x32_bf16(ah, bh, acc, 0, 0, 0);
        acc = __builtin_amdgcn_mfma_f32_16x16x32_bf16(al, bh, acc, 0, 0, 0);
        acc = __builtin_amdgcn_mfma_f32_16x16x32_bf16(ah, bl, acc, 0, 0, 0);
      }
      float bhhv = p.bhh[layer * FH_ + gc];
      int bc = q4 * 8 + (fc & 7);
#pragma unroll
      for (int reg = 0; reg < 4; ++reg)
        ldshh[(rowbase + lq * 4 + reg) * 33 + bc] = acc[reg] + bhhv;
    }
    __syncthreads();
    if (active) {
      float s1 = 0, q1 = 0, s2 = 0, q2 = 0;
#pragma unroll
      for (int q = 0; q < 4; ++q) {
        float a = ih[q];
        float b = ldshh[row * 33 + q * 8 + c8];
        hh[q] = b;
        s1 += a; q1 += a * a; s2 += b; q2 += b * b;
      }
#pragma unroll
      for (int o = 1; o < 8; o <<= 1) {
        s1 += __shfl_xor(s1, o); q1 += __shfl_xor(q1, o);
        s2 += __shfl_xor(s2, o); q2 += __shfl_xor(q2, o);
      }
      if (c8 == 0) {
        float* pb = p.part1 + ((size_t)(layer * 64 + row) * 4) * 128 + j;
        AST(pb + 0 * 128, s1); AST(pb + 1 * 128, q1);
        AST(pb + 2 * 128, s2); AST(pb + 3 * 128, q2);
      }
    }
    __syncthreads();
    if (tid == 0) AST(&p.f1[blk], g);

    // ================= phase B: summers reduce LN1 partials ================
    if (blk < 128) {
      waitf(p.f1, slayer * 128, 127, g, bmin);
      int st = tid >> 7, jj = tid & 127;
      float v = ALD(p.part1 + ((size_t)(slayer * 64 + srow) * 4 + st) * 128 + jj);
#pragma unroll
      for (int o = 32; o; o >>= 1) v += __shfl_xor(v, o);
      if (l == 0) red8[w] = v;
      __syncthreads();
      if (tid < 4)
        AST(p.stats1 + (size_t)(slayer * 64 + srow) * 4 + tid, red8[tid * 2] + red8[tid * 2 + 1]);
      __syncthreads();
      if (tid == 0) AST(&p.f2[blk], g);
    }

    // ================= phase C: LN1 + gates + cell + cell partials =========
    waitf(p.f2, layer * 64, 63, g, bmin);
    float ogate = 0.0f;
    if (active) {
      const float* s1p = p.stats1 + (size_t)(layer * 64 + row) * 4;
      float S1 = ALD(s1p + 0), Q1 = ALD(s1p + 1), S2 = ALD(s1p + 2), Q2 = ALD(s1p + 3);
      const float inv4h = 1.0f / 4096.0f;
      float m1 = S1 * inv4h, m2 = S2 * inv4h;
      float i1 = rsqrtf(Q1 * inv4h - m1 * m1 + 1e-5f);
      float i2 = rsqrtf(Q2 * inv4h - m2 * m2 + 1e-5f);
      float pre[4];
#pragma unroll
      for (int q = 0; q < 4; ++q) {
        int gc = layer * FH_ + q * 1024 + hcol;
        pre[q] = p.gih[gc] * (ih[q] - m1) * i1 + p.beih[gc]
               + p.ghh[gc] * (hh[q] - m2) * i2 + p.behh[gc];
      }
      float iG = 1.0f / (1.0f + __expf(-pre[0]));
      float fG = 1.0f / (1.0f + __expf(-pre[1]));
      float oG = 1.0f / (1.0f + __expf(-pre[2]));
      float gG = tanhf(pre[3]);
      creg = fG * creg + iG * gG;
      ogate = oG;
      float sc = creg, sq = creg * creg;
#pragma unroll
      for (int o = 1; o < 8; o <<= 1) { sc += __shfl_xor(sc, o); sq += __shfl_xor(sq, o); }
      if (c8 == 0) {
        float* pb = p.part2 + ((size_t)(layer * 64 + row) * 2) * 128 + j;
        AST(pb + 0 * 128, sc); AST(pb + 1 * 128, sq);
      }
    }
    __syncthreads();
    if (tid == 0) AST(&p.f3[blk], g);

    // ================= phase D: summers reduce cell partials ===============
    if (blk < 128) {
      waitf(p.f3, slayer * 128, 127, g, bmin);
      if (tid < 256) {
        int st = tid >> 7, jj = tid & 127;
        float v = ALD(p.part2 + ((size_t)(slayer * 64 + srow) * 2 + st) * 128 + jj);
#pragma unroll
        for (int o = 32; o; o >>= 1) v += __shfl_xor(v, o);
        if (l == 0) red8[w] = v;
      }
      __syncthreads();
      if (tid < 2)
        AST(p.stats2 + (size_t)(slayer * 64 + srow) * 2 + tid, red8[tid * 2] + red8[tid * 2 + 1]);
      __syncthreads();
      if (tid == 0) AST(&p.f4[blk], g);
    }

    // ================= phase E: cell-LN + h + Y ============================
    waitf(p.f4, layer * 64, 63, g, bmin);
    if (active) {
      const float* s2p = p.stats2 + (size_t)(layer * 64 + row) * 2;
      float S3 = ALD(s2p + 0), Q3 = ALD(s2p + 1);
      const float invh = 1.0f / 1024.0f;
      float m3 = S3 * invh;
      float i3 = rsqrtf(Q3 * invh - m3 * m3 + 1e-5f);
      int hidx = layer * H_ + hcol;
      float hy = ogate * tanhf((creg - m3) * i3 * p.gho[hidx] + p.beho[hidx]);
      unsigned hv = f2bf(hy);
      unsigned lv = f2bf(hy - bf2f(hv));
      unsigned hv2 = (unsigned)__shfl_down((int)hv, 1);
      unsigned lv2 = (unsigned)__shfl_down((int)lv, 1);
      if ((c8 & 1) == 0) {
        size_t i32 = (((size_t)(slot * 2 + layer) * 64 + row) * 1024 + hcol) >> 1;
        AST((unsigned*)p.hpHi + i32, hv | (hv2 << 16));
        AST((unsigned*)p.hpLo + i32, lv | (lv2 << 16));
      }
      size_t yo = ((size_t)t0 * B_ + row) * H_ + hcol;
      p.XYhi[yo] = (unsigned short)hv;
      p.XYlo[yo] = (unsigned short)lv;
    }
    __syncthreads();
    if (tid == 0) AST(&p.fE[blk], g);
  }

  // ---- span epilogue: persist c-state ----
  p.cst[((size_t)(layer * B_ + row)) * H_ + hcol] = creg;
}

// ---------------------------------------------------------------------------
extern "C" void kernel_launch(void* const* d_in, const int* in_sizes, int n_in,
                              void* d_out, int out_size, void* d_ws, size_t ws_size,
                              hipStream_t stream) {
  const float* x    = (const float*)d_in[0];
  const float* w_ih = (const float*)d_in[1];
  const float* b_ih = (const float*)d_in[2];
  const float* w_hh = (const float*)d_in[3];
  const float* b_hh = (const float*)d_in[4];
  const float* g_ih = (const float*)d_in[5];
  const float* be_ih= (const float*)d_in[6];
  const float* g_hh = (const float*)d_in[7];
  const float* be_hh= (const float*)d_in[8];
  const float* g_ho = (const float*)d_in[9];
  const float* be_ho= (const float*)d_in[10];
  const float* fc_w = (const float*)d_in[11];
  const float* fc_b = (const float*)d_in[12];
  float* out = (float*)d_out;
  (void)ws_size; (void)in_sizes; (void)n_in; (void)out_size;

  // workspace carve-up (~249 MB)
  char* wsb = (char*)d_ws;
  size_t off = 0;
  unsigned short* wihHi  = (unsigned short*)(wsb + off); off += 16777216;
  unsigned short* wihLo  = (unsigned short*)(wsb + off); off += 16777216;
  unsigned short* whhF   = (unsigned short*)(wsb + off); off += 33554432;
  unsigned short* fcHi   = (unsigned short*)(wsb + off); off += 2097152;
  unsigned short* fcLo   = (unsigned short*)(wsb + off); off += 2097152;
  unsigned short* XYhi   = (unsigned short*)(wsb + off); off += 67108864;
  unsigned short* XYlo   = (unsigned short*)(wsb + off); off += 67108864;
  float* P0              = (float*)(wsb + off); off += (size_t)16 * B_ * FH_ * 4;
  float* P1              = (float*)(wsb + off); off += (size_t)16 * B_ * FH_ * 4;
  unsigned short* hpHi   = (unsigned short*)(wsb + off); off += 4194304;  // [16][2][64][1024]
  unsigned short* hpLo   = (unsigned short*)(wsb + off); off += 4194304;
  float* cst             = (float*)(wsb + off); off += 524288;
  float* part1           = (float*)(wsb + off); off += 524288;   // [2][64][4][128]
  float* part2           = (float*)(wsb + off); off += 262144;   // [2][64][2][128]
  float* stats1          = (float*)(wsb + off); off += 2048;
  float* stats2          = (float*)(wsb + off); off += 1024;
  unsigned* flags        = (unsigned*)(wsb + off); off += 8192;  // f1|f2|f3|f4|fE

  unsigned* f1 = flags;           // 256
  unsigned* f2 = flags + 256;     // 128
  unsigned* f3 = flags + 512;     // 256
  unsigned* f4 = flags + 768;     // 128
  unsigned* fE = flags + 1024;    // 256

  // --- weight prep ---
  {
    int n4 = 2 * FH_ * D_ / 4;
    cast_split_k<<<(n4 + 255) / 256, 256, 0, stream>>>((const float4*)w_ih, (us4*)wihHi, (us4*)wihLo, n4);
    int nf = H_ * H_ / 4;
    cast_split_k<<<(nf + 255) / 256, 256, 0, stream>>>((const float4*)fc_w, (us4*)fcHi, (us4*)fcLo, nf);
    int nx = T_ * B_ * D_ / 4;
    transpose_split_k<<<nx / 256, 256, 0, stream>>>((const float4*)x, (us4*)XYhi, (us4*)XYlo);
    whh_frag3_k<<<8192, 256, 0, stream>>>(w_hh, whhF);
  }

  // --- state init (graph nodes; re-run each replay) ---
  hipMemsetAsync(hpHi, 0, 8388608, stream);     // hpHi + hpLo contiguous
  hipMemsetAsync(cst, 0, 524288, stream);
  hipMemsetAsync(flags, 0, 8192, stream);

  hipFuncSetAttribute(reinterpret_cast<const void*>(span_k),
                      hipFuncAttributeMaxDynamicSharedMemorySize, SMEM_TOTAL);

  // --- recurrence: 33 span launches, chunk GEMMs interleaved ---
  SpanP prm;
  prm.whhF = whhF; prm.P0 = P0; prm.P1 = P1;
  prm.hpHi = hpHi; prm.hpLo = hpLo; prm.XYhi = XYhi; prm.XYlo = XYlo;
  prm.cst = cst;
  prm.bhh = b_hh; prm.gih = g_ih; prm.beih = be_ih;
  prm.ghh = g_hh; prm.behh = be_hh; prm.gho = g_ho; prm.beho = be_ho;
  prm.part1 = part1; prm.part2 = part2; prm.stats1 = stats1; prm.stats2 = stats2;
  prm.f1 = f1; prm.f2 = f2; prm.f3 = f3; prm.f4 = f4; prm.fE = fE;

  for (int c = 0; c < SPANS; ++c) {
    int s = c * NSPAN;
    if (s < T_) {
      gemm3_k<0><<<dim3(FH_ / 128, RCH_ / 128), 256, 0, stream>>>(
          XYhi + (size_t)s * B_ * D_, XYlo + (size_t)s * B_ * D_,
          wihHi, wihLo, b_ih, P0, D_, FH_);
    }
    if (s >= LAG_) {
      gemm3_k<0><<<dim3(FH_ / 128, RCH_ / 128), 256, 0, stream>>>(
          XYhi + (size_t)(s - LAG_) * B_ * D_, XYlo + (size_t)(s - LAG_) * B_ * D_,
          wihHi + (1 << 22), wihLo + (1 << 22), b_ih + FH_, P1, D_, FH_);
    }
    prm.s0 = s;
    span_k<<<256, 512, SMEM_TOTAL, stream>>>(prm);
  }

  // --- final FC: out[b][t][c] = Y1[t*B+b,:]·fc_w[c,:] + fc_b ---
  gemm3_k<1><<<dim3(H_ / 128, (T_ * B_) / 128), 256, 0, stream>>>(
      XYhi, XYlo, fcHi, fcLo, fc_b, out, H_, H_);
}

// Round 12
// 19474.658 us; speedup vs baseline: 2.3461x; 1.3068x over previous
//
#include <hip/hip_runtime.h>

// ---------------------------------------------------------------------------
// LayerNorm-LSTM (depth=2) + FC, MI355X. Split-bf16 (hi/lo) 3-term MFMA.
// Round 12: R10's PROVEN data paths (overwrite-only partials -> summer blocks
// -> stats; strip in LDS; h in sc1 rotating slots) with only the sync cost
// fixed: 8-way split counters + wave0-only polling, and wave0 ALD64 + LDS
// broadcast for stats reads. 33 span launches x 16 steps, Whh in 128KB LDS.
// ---------------------------------------------------------------------------

typedef __attribute__((ext_vector_type(8))) short short8;
typedef __attribute__((ext_vector_type(8))) __bf16 bf16x8;
typedef __attribute__((ext_vector_type(4))) float f32x4;
typedef __attribute__((ext_vector_type(4))) unsigned short us4;
typedef unsigned long long u64;

#define B_ 64
#define T_ 512
#define D_ 1024
#define H_ 1024
#define FH_ 4096
#define LAG_ 16
#define NSPAN 16
#define SPANS 33               // 33*16 = 528 = T + LAG
#define RCH_ (B_ * 16)

#define SMEM_WHH 131072
#define SMEM_STRIP 8448                           // ldshh [64][33] f32
#define SMEM_TOTAL (SMEM_WHH + SMEM_STRIP + 1024) // + statsL [256] f32

typedef const __attribute__((address_space(1))) unsigned int* gas_ptr;
typedef __attribute__((address_space(3))) unsigned int* las_ptr;
#define GLOAD_LDS16(g, l) \
  __builtin_amdgcn_global_load_lds((gas_ptr)(g), (las_ptr)(l), 16, 0, 0)

#define ALD(p)    __hip_atomic_load((p), __ATOMIC_RELAXED, __HIP_MEMORY_SCOPE_AGENT)
#define ALD64(p)  __hip_atomic_load((p), __ATOMIC_RELAXED, __HIP_MEMORY_SCOPE_AGENT)
#define AST(p, v) __hip_atomic_store((p), (v), __ATOMIC_RELAXED, __HIP_MEMORY_SCOPE_AGENT)

static __device__ __forceinline__ unsigned short f2bf(float f) {
  unsigned int u = __builtin_bit_cast(unsigned int, f);
  u += 0x7FFFu + ((u >> 16) & 1u);   // round-to-nearest-even
  return (unsigned short)(u >> 16);
}
static __device__ __forceinline__ float bf2f(unsigned short u) {
  unsigned int x = ((unsigned int)u) << 16;
  return __builtin_bit_cast(float, x);
}

// ---------------- split-cast fp32 -> (hi, lo) bf16 ----------------
__global__ void cast_split_k(const float4* __restrict__ in,
                             us4* __restrict__ hi, us4* __restrict__ lo, int n4) {
  int i = blockIdx.x * 256 + threadIdx.x;
  if (i < n4) {
    float4 v = in[i];
    us4 h, l;
    h[0] = f2bf(v.x); l[0] = f2bf(v.x - bf2f(h[0]));
    h[1] = f2bf(v.y); l[1] = f2bf(v.y - bf2f(h[1]));
    h[2] = f2bf(v.z); l[2] = f2bf(v.z - bf2f(h[2]));
    h[3] = f2bf(v.w); l[3] = f2bf(v.w - bf2f(h[3]));
    hi[i] = h; lo[i] = l;
  }
}

// ------ transpose-split input [B][T][D] f32 -> [T][B][D] (hi, lo) bf16 -----
__global__ void transpose_split_k(const float4* __restrict__ x,
                                  us4* __restrict__ hi, us4* __restrict__ lo) {
  int i = blockIdx.x * 256 + threadIdx.x;
  int d4  = i & 255;
  int rem = i >> 8;
  int b = rem & 63;
  int t = rem >> 6;
  float4 v = x[((size_t)(b * T_ + t) << 8) + d4];
  us4 h, l;
  h[0] = f2bf(v.x); l[0] = f2bf(v.x - bf2f(h[0]));
  h[1] = f2bf(v.y); l[1] = f2bf(v.y - bf2f(h[1]));
  h[2] = f2bf(v.z); l[2] = f2bf(v.z - bf2f(h[2]));
  h[3] = f2bf(v.w); l[3] = f2bf(v.w - bf2f(h[3]));
  size_t o = ((size_t)(t * B_ + b) << 8) + d4;
  hi[o] = h; lo[o] = l;
}

// ------ fragment-ordered Whh (hi AND lo), gate-interleaved (R8/R10-proven) --
__global__ void whh_frag3_k(const float* __restrict__ w_hh,
                            unsigned short* __restrict__ frag) {
  int i = blockIdx.x * 256 + threadIdx.x;    // 2,097,152 chunks
  int lane = i & 63;
  int kc   = (i >> 6) & 31;
  int g    = (i >> 11) & 1;
  int sel  = (i >> 12) & 1;
  int j    = (i >> 13) & 127;
  int layer= (i >> 20) & 1;
  int fc = lane & 15;
  int gc = (g * 2 + (fc >> 3)) * 1024 + j * 8 + (fc & 7);
  int k0 = kc * 32 + (lane >> 4) * 8;
  const float* src = w_hh + ((size_t)layer * FH_ + gc) * 1024 + k0;
  short8 o;
#pragma unroll
  for (int e = 0; e < 8; ++e) {
    float v = src[e];
    unsigned short h = f2bf(v);
    o[e] = sel ? (short)f2bf(v - bf2f(h)) : (short)h;
  }
  *(short8*)(frag + (size_t)i * 8) = o;
}

// ---------------- 3-term split-bf16 GEMM (chunk projections + FC) ----------
template <int FCMODE>
__global__ __launch_bounds__(256) void gemm3_k(
    const unsigned short* __restrict__ Ahi, const unsigned short* __restrict__ Alo,
    const unsigned short* __restrict__ Whi, const unsigned short* __restrict__ Wlo,
    const float* __restrict__ bias, float* __restrict__ out, int K, int N) {
  __shared__ unsigned short lAh[128 * 40];
  __shared__ unsigned short lAl[128 * 40];
  __shared__ unsigned short lWh[128 * 40];
  __shared__ unsigned short lWl[128 * 40];
  int tid = threadIdx.x;
  int l = tid & 63, w = tid >> 6;
  int r0 = blockIdx.y * 128, c0 = blockIdx.x * 128;
  int wr = (w >> 1) * 64, wc = (w & 1) * 64;
  int lr = l & 15, lk = (l >> 4) * 8;
  f32x4 acc[4][4] = {};
  int srow = tid >> 2;
  int scc  = (tid & 3) * 8;

  for (int kt = 0; kt < K; kt += 32) {
#pragma unroll
    for (int i = 0; i < 2; ++i) {
      int row = srow + i * 64;
      size_t aoff = (size_t)(r0 + row) * K + kt + scc;
      size_t woff = (size_t)(c0 + row) * K + kt + scc;
      *(short8*)&lAh[row * 40 + scc] = *(const short8*)(Ahi + aoff);
      *(short8*)&lAl[row * 40 + scc] = *(const short8*)(Alo + aoff);
      *(short8*)&lWh[row * 40 + scc] = *(const short8*)(Whi + woff);
      *(short8*)&lWl[row * 40 + scc] = *(const short8*)(Wlo + woff);
    }
    __syncthreads();
    bf16x8 ah[4], al[4], bh[4], bl[4];
#pragma unroll
    for (int mi = 0; mi < 4; ++mi) {
      ah[mi] = *(bf16x8*)&lAh[(wr + mi * 16 + lr) * 40 + lk];
      al[mi] = *(bf16x8*)&lAl[(wr + mi * 16 + lr) * 40 + lk];
    }
#pragma unroll
    for (int ni = 0; ni < 4; ++ni) {
      bh[ni] = *(bf16x8*)&lWh[(wc + ni * 16 + lr) * 40 + lk];
      bl[ni] = *(bf16x8*)&lWl[(wc + ni * 16 + lr) * 40 + lk];
    }
#pragma unroll
    for (int mi = 0; mi < 4; ++mi)
#pragma unroll
      for (int ni = 0; ni < 4; ++ni) {
        acc[mi][ni] = __builtin_amdgcn_mfma_f32_16x16x32_bf16(ah[mi], bh[ni], acc[mi][ni], 0, 0, 0);
        acc[mi][ni] = __builtin_amdgcn_mfma_f32_16x16x32_bf16(ah[mi], bl[ni], acc[mi][ni], 0, 0, 0);
        acc[mi][ni] = __builtin_amdgcn_mfma_f32_16x16x32_bf16(al[mi], bh[ni], acc[mi][ni], 0, 0, 0);
      }
    __syncthreads();
  }

#pragma unroll
  for (int mi = 0; mi < 4; ++mi)
#pragma unroll
    for (int ni = 0; ni < 4; ++ni)
#pragma unroll
      for (int reg = 0; reg < 4; ++reg) {
        int r = r0 + wr + mi * 16 + (l >> 4) * 4 + reg;
        int c = c0 + wc + ni * 16 + lr;
        float v = acc[mi][ni][reg] + bias[c];
        if (FCMODE) {
          int b = r & 63, t = r >> 6;
          out[((size_t)b * T_ + t) * (size_t)N + c] = v;
        } else {
          out[(size_t)r * N + c] = v;
        }
      }
}

// ---------------- span kernel ----------------
struct SpanP {
  const unsigned short* whhF;
  const float *P0, *P1;
  unsigned short *hpHi, *hpLo;     // [16 slot][2 layer][64][1024]
  unsigned short *XYhi, *XYlo;
  float* cst;
  const float *bhh, *gih, *beih, *ghh, *behh, *gho, *beho;
  float *part1, *part2;            // [2][64][4][128] / [2][64][2][128]
  float *stats1, *stats2;          // [2][64][4] / [2][64][2]
  unsigned *cnt;                   // 5 sets x [2 layer][8 sub x 16-pad]
  int s0;
};

// sub-counter sets (each [2][8], padded stride 16 u32 = 64B per sub)
#define CSET(set, layer) (p.cnt + ((set) * 2 + (layer)) * 128)

// wave0-only poll of 8 padded sub-counters; other waves park at barrier.
static __device__ __forceinline__ void waitc(const unsigned* c, unsigned tgt) {
  if (threadIdx.x < 64) {
    int l = threadIdx.x;
    for (;;) {
      unsigned v = 0xffffffffu;
      if (l < 8) v = ALD(c + l * 16);
#pragma unroll
      for (int o = 4; o; o >>= 1) {
        unsigned u = (unsigned)__shfl_xor((int)v, o);
        v = v < u ? v : u;
      }
      v = (unsigned)__shfl((int)v, 0);
      if (v >= tgt) break;
      __builtin_amdgcn_s_sleep(2);
    }
  }
  __syncthreads();
}

__global__ __launch_bounds__(512) void span_k(SpanP p) {
  extern __shared__ char smem[];
  unsigned short* wl = (unsigned short*)smem;            // 128KB Whh frags
  float* ldshh = (float*)(smem + SMEM_WHH);              // [64][33]
  float* statsL = (float*)(smem + SMEM_WHH + SMEM_STRIP);// [256]
  __shared__ float red8[8];

  const int tid = threadIdx.x;
  const int blk = blockIdx.x;
  const int layer = blk >> 7;        // hh-role layer
  const int j = blk & 127;
  const int w = tid >> 6, l = tid & 63;
  const int lr = l & 15, lq = l >> 4;
  const int slayer = blk >> 6;       // summer-role layer (blk<128)
  const int srow = blk & 63;         // summer-role row
  const int row = tid >> 3, c8 = tid & 7;
  const int hcol = j * 8 + c8;
  const int subj = j & 7;            // hh-role sub-counter
  const int subs = srow & 7;         // summer-role sub-counter

  // ---- stage Whh hi+lo frag slice (once per span) ----
  {
    const unsigned short* gsrc = p.whhF + ((size_t)blk << 16);
#pragma unroll
    for (int r = 0; r < 16; ++r) {
      int c = r * 512 + tid;
      GLOAD_LDS16(gsrc + (size_t)c * 8, wl + (size_t)c * 8);
    }
  }

  // ---- cache per-thread params for the whole span ----
  float gihv[4], beihv[4], ghhv[4], behhv[4];
#pragma unroll
  for (int q = 0; q < 4; ++q) {
    int gc = layer * FH_ + q * 1024 + hcol;
    gihv[q] = p.gih[gc]; beihv[q] = p.beih[gc];
    ghhv[q] = p.ghh[gc]; behhv[q] = p.behh[gc];
  }
  float ghov  = p.gho[layer * H_ + hcol];
  float behov = p.beho[layer * H_ + hcol];
  // strip-write bias for this thread's (wave colgroup, fragment col)
  const int gch = w & 1;
  const int q4 = gch * 2 + (lr >> 3);
  const float bhhv = p.bhh[layer * FH_ + q4 * 1024 + j * 8 + (lr & 7)];
  float creg = p.cst[((size_t)(layer * B_ + row)) * H_ + hcol];

  __syncthreads();   // staging drained (vmcnt 0)

  for (int sl = 0; sl < NSPAN; ++sl) {
    const int s = p.s0 + sl;
    const unsigned g = (unsigned)(s + 1);
    const int t0 = layer ? (s - LAG_) : s;
    const bool active = (t0 >= 0) && (t0 < T_);
    const int slotp = (sl - 1) & 15;
    const int slot = sl;

    // ============ phase A: hh MFMA + strip + LN1 partial stores ============
    waitc(CSET(4, layer), 16u * (g - 1));
    float ih[4] = {0, 0, 0, 0}, hh[4] = {0, 0, 0, 0};
    if (active) {
      const float* Pb = layer ? p.P1 : p.P0;
#pragma unroll
      for (int q = 0; q < 4; ++q)
        ih[q] = Pb[((size_t)(sl * B_ + row)) * FH_ + q * 1024 + hcol];

      const int rf = w >> 1;
      const int rowbase = rf * 16;
      const unsigned short* hHb = p.hpHi + ((size_t)(slotp * 2 + layer)) * 65536;
      const unsigned short* hLb = p.hpLo + ((size_t)(slotp * 2 + layer)) * 65536;
      f32x4 acc = {};
#pragma unroll 8
      for (int kc = 0; kc < 32; ++kc) {
        int k = kc * 32 + lq * 8;
        bf16x8 ah = __builtin_bit_cast(bf16x8, *(const short8*)(hHb + (rowbase + lr) * 1024 + k));
        bf16x8 al = __builtin_bit_cast(bf16x8, *(const short8*)(hLb + (rowbase + lr) * 1024 + k));
        bf16x8 bh = __builtin_bit_cast(bf16x8, *(const short8*)&wl[(size_t)(gch * 2048 + kc * 64 + l) * 8]);
        bf16x8 bl = __builtin_bit_cast(bf16x8, *(const short8*)&wl[(size_t)(4096 + gch * 2048 + kc * 64 + l) * 8]);
        acc = __builtin_amdgcn_mfma_f32_16x16x32_bf16(ah, bh, acc, 0, 0, 0);
        acc = __builtin_amdgcn_mfma_f32_16x16x32_bf16(al, bh, acc, 0, 0, 0);
        acc = __builtin_amdgcn_mfma_f32_16x16x32_bf16(ah, bl, acc, 0, 0, 0);
      }
      int bc = q4 * 8 + (lr & 7);
#pragma unroll
      for (int reg = 0; reg < 4; ++reg)
        ldshh[(rowbase + lq * 4 + reg) * 33 + bc] = acc[reg] + bhhv;
    }
    __syncthreads();
    if (active) {
      float s1 = 0, q1 = 0, s2 = 0, q2 = 0;
#pragma unroll
      for (int q = 0; q < 4; ++q) {
        float a = ih[q];
        float b = ldshh[row * 33 + q * 8 + c8];
        hh[q] = b;
        s1 += a; q1 += a * a; s2 += b; q2 += b * b;
      }
#pragma unroll
      for (int o = 1; o < 8; o <<= 1) {
        s1 += __shfl_xor(s1, o); q1 += __shfl_xor(q1, o);
        s2 += __shfl_xor(s2, o); q2 += __shfl_xor(q2, o);
      }
      if (c8 == 0) {
        float* pb = p.part1 + ((size_t)(layer * 64 + row) * 4) * 128 + j;
        AST(pb + 0 * 128, s1); AST(pb + 1 * 128, q1);
        AST(pb + 2 * 128, s2); AST(pb + 3 * 128, q2);
      }
    }
    __syncthreads();
    if (tid == 0) atomicAdd(CSET(0, layer) + subj * 16, 1u);

    // ============ phase B: summers reduce LN1 partials =====================
    if (blk < 128) {
      waitc(CSET(0, slayer), 16u * g);
      int st = tid >> 7, jj = tid & 127;
      float v = ALD(p.part1 + ((size_t)(slayer * 64 + srow) * 4 + st) * 128 + jj);
#pragma unroll
      for (int o = 32; o; o >>= 1) v += __shfl_xor(v, o);
      if (l == 0) red8[w] = v;
      __syncthreads();
      if (tid < 4)
        AST(p.stats1 + (size_t)(slayer * 64 + srow) * 4 + tid, red8[tid * 2] + red8[tid * 2 + 1]);
      __syncthreads();
      if (tid == 0) atomicAdd(CSET(1, slayer) + subs * 16, 1u);
    }

    // ============ phase C: LN1 + gates + cell + cell partial stores ========
    waitc(CSET(1, layer), 8u * g);
    if (tid < 64) {
      const u64* sp = (const u64*)(p.stats1 + (size_t)layer * 256);
      u64 a = ALD64(sp + tid);
      u64 b = ALD64(sp + 64 + tid);
      ((u64*)statsL)[tid] = a;
      ((u64*)statsL)[64 + tid] = b;
    }
    __syncthreads();
    float ogate = 0.0f;
    if (active) {
      float S1 = statsL[row * 4 + 0], Q1 = statsL[row * 4 + 1];
      float S2 = statsL[row * 4 + 2], Q2 = statsL[row * 4 + 3];
      const float inv4h = 1.0f / 4096.0f;
      float m1 = S1 * inv4h, m2 = S2 * inv4h;
      float i1 = rsqrtf(Q1 * inv4h - m1 * m1 + 1e-5f);
      float i2 = rsqrtf(Q2 * inv4h - m2 * m2 + 1e-5f);
      float pre[4];
#pragma unroll
      for (int q = 0; q < 4; ++q)
        pre[q] = gihv[q] * (ih[q] - m1) * i1 + beihv[q]
               + ghhv[q] * (hh[q] - m2) * i2 + behhv[q];
      float iG = 1.0f / (1.0f + __expf(-pre[0]));
      float fG = 1.0f / (1.0f + __expf(-pre[1]));
      float oG = 1.0f / (1.0f + __expf(-pre[2]));
      float gG = tanhf(pre[3]);
      creg = fG * creg + iG * gG;
      ogate = oG;
      float sc = creg, sq = creg * creg;
#pragma unroll
      for (int o = 1; o < 8; o <<= 1) { sc += __shfl_xor(sc, o); sq += __shfl_xor(sq, o); }
      if (c8 == 0) {
        float* pb = p.part2 + ((size_t)(layer * 64 + row) * 2) * 128 + j;
        AST(pb + 0 * 128, sc); AST(pb + 1 * 128, sq);
      }
    }
    __syncthreads();
    if (tid == 0) atomicAdd(CSET(2, layer) + subj * 16, 1u);

    // ============ phase D: summers reduce cell partials ====================
    if (blk < 128) {
      waitc(CSET(2, slayer), 16u * g);
      if (tid < 256) {
        int st = tid >> 7, jj = tid & 127;
        float v = ALD(p.part2 + ((size_t)(slayer * 64 + srow) * 2 + st) * 128 + jj);
#pragma unroll
        for (int o = 32; o; o >>= 1) v += __shfl_xor(v, o);
        if (l == 0) red8[w] = v;
      }
      __syncthreads();
      if (tid < 2)
        AST(p.stats2 + (size_t)(slayer * 64 + srow) * 2 + tid, red8[tid * 2] + red8[tid * 2 + 1]);
      __syncthreads();
      if (tid == 0) atomicAdd(CSET(3, slayer) + subs * 16, 1u);
    }

    // ============ phase E: cell-LN + h + Y =================================
    waitc(CSET(3, layer), 8u * g);
    if (tid < 64) {
      const u64* sp2 = (const u64*)(p.stats2 + (size_t)layer * 128);
      ((u64*)statsL)[tid] = ALD64(sp2 + tid);
    }
    __syncthreads();
    if (active) {
      float S3 = statsL[row * 2 + 0], Q3 = statsL[row * 2 + 1];
      const float invh = 1.0f / 1024.0f;
      float m3 = S3 * invh;
      float i3 = rsqrtf(Q3 * invh - m3 * m3 + 1e-5f);
      float hy = ogate * tanhf((creg - m3) * i3 * ghov + behov);
      unsigned hv = f2bf(hy);
      unsigned lv = f2bf(hy - bf2f(hv));
      unsigned hv2 = (unsigned)__shfl_down((int)hv, 1);
      unsigned lv2 = (unsigned)__shfl_down((int)lv, 1);
      if ((c8 & 1) == 0) {
        size_t i32 = (((size_t)(slot * 2 + layer) * 64 + row) * 1024 + hcol) >> 1;
        AST((unsigned*)p.hpHi + i32, hv | (hv2 << 16));
        AST((unsigned*)p.hpLo + i32, lv | (lv2 << 16));
      }
      size_t yo = ((size_t)t0 * B_ + row) * H_ + hcol;
      p.XYhi[yo] = (unsigned short)hv;
      p.XYlo[yo] = (unsigned short)lv;
    }
    __syncthreads();
    if (tid == 0) atomicAdd(CSET(4, layer) + subj * 16, 1u);
  }

  // ---- span epilogue: persist c-state ----
  p.cst[((size_t)(layer * B_ + row)) * H_ + hcol] = creg;
}

// ---------------------------------------------------------------------------
extern "C" void kernel_launch(void* const* d_in, const int* in_sizes, int n_in,
                              void* d_out, int out_size, void* d_ws, size_t ws_size,
                              hipStream_t stream) {
  const float* x    = (const float*)d_in[0];
  const float* w_ih = (const float*)d_in[1];
  const float* b_ih = (const float*)d_in[2];
  const float* w_hh = (const float*)d_in[3];
  const float* b_hh = (const float*)d_in[4];
  const float* g_ih = (const float*)d_in[5];
  const float* be_ih= (const float*)d_in[6];
  const float* g_hh = (const float*)d_in[7];
  const float* be_hh= (const float*)d_in[8];
  const float* g_ho = (const float*)d_in[9];
  const float* be_ho= (const float*)d_in[10];
  const float* fc_w = (const float*)d_in[11];
  const float* fc_b = (const float*)d_in[12];
  float* out = (float*)d_out;
  (void)ws_size; (void)in_sizes; (void)n_in; (void)out_size;

  // workspace carve-up (~248 MB)
  char* wsb = (char*)d_ws;
  size_t off = 0;
  unsigned short* wihHi  = (unsigned short*)(wsb + off); off += 16777216;
  unsigned short* wihLo  = (unsigned short*)(wsb + off); off += 16777216;
  unsigned short* whhF   = (unsigned short*)(wsb + off); off += 33554432;
  unsigned short* fcHi   = (unsigned short*)(wsb + off); off += 2097152;
  unsigned short* fcLo   = (unsigned short*)(wsb + off); off += 2097152;
  unsigned short* XYhi   = (unsigned short*)(wsb + off); off += 67108864;
  unsigned short* XYlo   = (unsigned short*)(wsb + off); off += 67108864;
  float* P0              = (float*)(wsb + off); off += (size_t)16 * B_ * FH_ * 4;
  float* P1              = (float*)(wsb + off); off += (size_t)16 * B_ * FH_ * 4;
  unsigned short* hpHi   = (unsigned short*)(wsb + off); off += 4194304;  // [16][2][64][1024]
  unsigned short* hpLo   = (unsigned short*)(wsb + off); off += 4194304;
  float* cst             = (float*)(wsb + off); off += 524288;
  float* part1           = (float*)(wsb + off); off += 524288;   // [2][64][4][128]
  float* part2           = (float*)(wsb + off); off += 262144;   // [2][64][2][128]
  float* stats1          = (float*)(wsb + off); off += 2048;     // [2][64][4]
  float* stats2          = (float*)(wsb + off); off += 1024;     // [2][64][2]
  unsigned* cnt          = (unsigned*)(wsb + off); off += 5120;  // 5 sets x [2][8x16]

  // --- weight prep ---
  {
    int n4 = 2 * FH_ * D_ / 4;
    cast_split_k<<<(n4 + 255) / 256, 256, 0, stream>>>((const float4*)w_ih, (us4*)wihHi, (us4*)wihLo, n4);
    int nf = H_ * H_ / 4;
    cast_split_k<<<(nf + 255) / 256, 256, 0, stream>>>((const float4*)fc_w, (us4*)fcHi, (us4*)fcLo, nf);
    int nx = T_ * B_ * D_ / 4;
    transpose_split_k<<<nx / 256, 256, 0, stream>>>((const float4*)x, (us4*)XYhi, (us4*)XYlo);
    whh_frag3_k<<<8192, 256, 0, stream>>>(w_hh, whhF);
  }

  // --- state init (graph nodes; re-run each replay) ---
  hipMemsetAsync(hpHi, 0, 8388608, stream);            // hpHi+hpLo contiguous
  hipMemsetAsync(cst, 0, 524288, stream);
  hipMemsetAsync(cnt, 0, 5120, stream);

  hipFuncSetAttribute(reinterpret_cast<const void*>(span_k),
                      hipFuncAttributeMaxDynamicSharedMemorySize, SMEM_TOTAL);

  // --- recurrence: 33 span launches, chunk GEMMs interleaved ---
  SpanP prm;
  prm.whhF = whhF; prm.P0 = P0; prm.P1 = P1;
  prm.hpHi = hpHi; prm.hpLo = hpLo; prm.XYhi = XYhi; prm.XYlo = XYlo;
  prm.cst = cst;
  prm.bhh = b_hh; prm.gih = g_ih; prm.beih = be_ih;
  prm.ghh = g_hh; prm.behh = be_hh; prm.gho = g_ho; prm.beho = be_ho;
  prm.part1 = part1; prm.part2 = part2; prm.stats1 = stats1; prm.stats2 = stats2;
  prm.cnt = cnt;

  for (int c = 0; c < SPANS; ++c) {
    int s = c * NSPAN;
    if (s < T_) {
      gemm3_k<0><<<dim3(FH_ / 128, RCH_ / 128), 256, 0, stream>>>(
          XYhi + (size_t)s * B_ * D_, XYlo + (size_t)s * B_ * D_,
          wihHi, wihLo, b_ih, P0, D_, FH_);
    }
    if (s >= LAG_) {
      gemm3_k<0><<<dim3(FH_ / 128, RCH_ / 128), 256, 0, stream>>>(
          XYhi + (size_t)(s - LAG_) * B_ * D_, XYlo + (size_t)(s - LAG_) * B_ * D_,
          wihHi + (1 << 22), wihLo + (1 << 22), b_ih + FH_, P1, D_, FH_);
    }
    prm.s0 = s;
    span_k<<<256, 512, SMEM_TOTAL, stream>>>(prm);
  }

  // --- final FC: out[b][t][c] = Y1[t*B+b,:]·fc_w[c,:] + fc_b ---
  gemm3_k<1><<<dim3(H_ / 128, (T_ * B_) / 128), 256, 0, stream>>>(
      XYhi, XYlo, fcHi, fcLo, fc_b, out, H_, H_);
}